// Round 13
// baseline (249.413 us; speedup 1.0000x reference)
//
#include <hip/hip_runtime.h>

typedef _Float16 h2 __attribute__((ext_vector_type(2)));
typedef _Float16 h4 __attribute__((ext_vector_type(4)));
typedef _Float16 h8 __attribute__((ext_vector_type(8)));
typedef float    f4 __attribute__((ext_vector_type(4)));

#define MFMA32(a,b,c) __builtin_amdgcn_mfma_f32_16x16x32_f16((a),(b),(c),0,0,0)
#define MFMA16(a,b,c) __builtin_amdgcn_mfma_f32_16x16x16f16((a),(b),(c),0,0,0)

#define B_N 8
#define C_N 384
#define P_N 4096
#define PI_F 3.14159265358979323846f

__device__ __forceinline__ h4 to_h4(f4 v) {
  h4 r; r[0]=(_Float16)v[0]; r[1]=(_Float16)v[1]; r[2]=(_Float16)v[2]; r[3]=(_Float16)v[3];
  return r;
}

// async global->LDS, 16B per lane; LDS dest = wave-uniform base + lane*16 (m97/m104)
__device__ __forceinline__ void gl_lds16(const _Float16* g, _Float16* l) {
  __builtin_amdgcn_global_load_lds(
      (const __attribute__((address_space(1))) void*)g,
      (__attribute__((address_space(3))) void*)l, 16, 0, 0);
}

// one K-step: counted vmcnt + raw barriers (T3/T4 minimum form), T2 chunk-XOR
// swizzle (pre-swizzled global src, swizzled ds_read; LDS dest linear).
__device__ __forceinline__ void gemm_step(
    const _Float16* __restrict__ ga, const _Float16* __restrict__ gb,
    int kcn, bool pref,
    _Float16* laC, _Float16* lbC, _Float16* laN, _Float16* lbN,
    f4 (&acc)[4][4]) {
  int t = threadIdx.x, lane = t & 63, wave = t >> 6;
  int quad = lane >> 4, l15 = lane & 15;
  int wm = wave >> 1, wn = wave & 1;
  int s_row = lane >> 2;
  if (pref) {
    #pragma unroll
    for (int s = 0; s < 2; s++) {
      int seg = wave * 2 + s;
      int row = seg * 16 + s_row;
      gl_lds16(ga + (size_t)row*384 + kcn, &laN[seg*512 + lane*8]);
      gl_lds16(gb + (size_t)row*384 + kcn, &lbN[seg*512 + lane*8]);
    }
    // wait own PREVIOUS step's 4 staging loads (oldest); 4 new stay in flight
    asm volatile("s_waitcnt vmcnt(4)" ::: "memory");
  } else {
    asm volatile("s_waitcnt vmcnt(0)" ::: "memory");
  }
  __builtin_amdgcn_s_barrier();          // all waves: current buffers staged
  asm volatile("" ::: "memory");
  h8 af[4], bf[4];
  int sq = (quad ^ (l15 & 3)) * 8;       // read-side swizzle (row&3 == l15&3)
  #pragma unroll
  for (int i = 0; i < 4; i++) {
    af[i] = *(const h8*)&laC[(wm*64 + i*16 + l15)*32 + sq];
    bf[i] = *(const h8*)&lbC[(wn*64 + i*16 + l15)*32 + sq];
  }
  asm volatile("s_waitcnt lgkmcnt(0)" ::: "memory");
  __builtin_amdgcn_s_barrier();          // all waves: reads done -> overwrite ok
  asm volatile("" ::: "memory");
  #pragma unroll
  for (int i = 0; i < 4; i++)
  #pragma unroll
  for (int j = 0; j < 4; j++)
    acc[i][j] = MFMA32(af[i], bf[j], acc[i][j]);
}

// ---------- setup: fp32->fp16 weights + DCT matrices ----------
__global__ __launch_bounds__(256) void k_setup(
    const float* __restrict__ lin_w, const float* __restrict__ tok_w,
    const float* __restrict__ out_w, _Float16* __restrict__ lwh,
    _Float16* __restrict__ twh, _Float16* __restrict__ owh,
    _Float16* __restrict__ wmg, _Float16* __restrict__ wmtg) {
  int t = blockIdx.x * 256 + threadIdx.x;
  if (t < 768*384) lwh[t] = (_Float16)lin_w[t];
  if (t < 384*384) { twh[t] = (_Float16)tok_w[t]; owh[t] = (_Float16)out_w[t]; }
  if (t < 4096) {
    int n = t >> 6, h = t & 63;
    float v = cosf((float)n * ((float)h + 0.5f) * (PI_F / 64.0f)) * 0.1767766952966369f;
    if (n == 0) v *= 0.7071067811865476f;
    wmg[n*64 + h]  = (_Float16)v;
    wmtg[h*64 + n] = (_Float16)v;
  }
}

// ---------- depthwise 3x3 conv, h-strip of 4 rows -> xdw[b][p][c] fp16 ----------
__global__ __launch_bounds__(256) void k_dwconv(
    const float* __restrict__ x, const float* __restrict__ dww,
    const float* __restrict__ dwb, _Float16* __restrict__ xdw) {
  int blk = blockIdx.x;
  int hs = blk & 15;            // 16 strips of 4 h-rows
  int rest = blk >> 4;
  int cgi = rest % 6;
  int b = rest / 6;
  int c0 = cgi * 64;
  int h0 = hs * 4;
  int t = threadIdx.x;
  __shared__ float wsm[576];
  __shared__ float bsm[64];
  __shared__ _Float16 buf[4][64 * 68];
  for (int i = t; i < 576; i += 256) wsm[i] = dww[c0*9 + i];
  if (t < 64) bsm[t] = dwb[c0 + t];
  __syncthreads();
  int lane = t & 63;
  int wslot = lane & 15, w4 = wslot * 4;
  int cs = t >> 4;              // 16 slots x 4 channels
  bool wlo = (wslot == 0), whi = (wslot == 15);
  int lm = (lane - 1) & 63, lp = (lane + 1) & 63;
  const float* xb = x + (size_t)b * C_N * P_N + w4;
  f4 prev[4], cur[4];
  float pL[4], pR[4], cL[4], cR[4];
  #pragma unroll
  for (int q = 0; q < 4; q++) {
    const float* xc = xb + (size_t)(c0 + cs*4 + q) * P_N;
    prev[q] = (h0 > 0) ? *(const f4*)(xc + (h0-1)*64) : f4{0.f,0.f,0.f,0.f};
    cur[q]  = *(const f4*)(xc + h0*64);
    pL[q] = __shfl(prev[q][3], lm, 64); pR[q] = __shfl(prev[q][0], lp, 64);
    cL[q] = __shfl(cur[q][3],  lm, 64); cR[q] = __shfl(cur[q][0],  lp, 64);
    if (wlo) { pL[q] = 0.f; cL[q] = 0.f; }
    if (whi) { pR[q] = 0.f; cR[q] = 0.f; }
  }
  #pragma unroll
  for (int r = 0; r < 4; r++) {
    int h = h0 + r;
    float o[4][4];
    #pragma unroll
    for (int q = 0; q < 4; q++) {
      int lc = cs*4 + q;
      const float* xc = xb + (size_t)(c0 + lc) * P_N;
      f4 nxt = (h < 63) ? *(const f4*)(xc + (h+1)*64) : f4{0.f,0.f,0.f,0.f};
      float nL = __shfl(nxt[3], lm, 64), nR = __shfl(nxt[0], lp, 64);
      if (wlo) nL = 0.f;
      if (whi) nR = 0.f;
      float k0=wsm[lc*9+0],k1=wsm[lc*9+1],k2=wsm[lc*9+2];
      float k3=wsm[lc*9+3],k4=wsm[lc*9+4],k5=wsm[lc*9+5];
      float k6=wsm[lc*9+6],k7=wsm[lc*9+7],k8=wsm[lc*9+8];
      float bias = bsm[lc];
      #pragma unroll
      for (int e = 0; e < 4; e++) {
        float tl = (e > 0) ? prev[q][e-1] : pL[q];
        float tr = (e < 3) ? prev[q][e+1] : pR[q];
        float ml = (e > 0) ? cur[q][e-1]  : cL[q];
        float mr = (e < 3) ? cur[q][e+1]  : cR[q];
        float bl = (e > 0) ? nxt[e-1]     : nL;
        float br = (e < 3) ? nxt[e+1]     : nR;
        float acc = bias;
        acc += k0*tl + k1*prev[q][e] + k2*tr;
        acc += k3*ml + k4*cur[q][e]  + k5*mr;
        acc += k6*bl + k7*nxt[e]     + k8*br;
        o[q][e] = acc;
      }
      prev[q] = cur[q]; pL[q] = cL[q]; pR[q] = cR[q];
      cur[q] = nxt;     cL[q] = nL;    cR[q] = nR;
    }
    #pragma unroll
    for (int e = 0; e < 4; e++) {
      h4 hv;
      #pragma unroll
      for (int q = 0; q < 4; q++) hv[q] = (_Float16)o[q][e];
      *(h4*)&buf[r][(w4 + e) * 68 + cs * 4] = hv;
    }
  }
  __syncthreads();
  #pragma unroll
  for (int r = 0; r < 4; r++) {
    _Float16* op = xdw + ((size_t)b*P_N + (h0 + r)*64) * C_N + c0;
    #pragma unroll
    for (int i = 0; i < 4; i++) {
      int flat = (t + 256*i) * 4;
      int pix = flat >> 6, cl = flat & 63;
      *(h4*)&op[(size_t)pix*C_N + cl] = *(const h4*)&buf[r][pix*68 + cl];
    }
  }
}

// ---------- tok GEMM + trig gate ----------
__global__ __launch_bounds__(256) void k_gate(
    const float* __restrict__ fe, const _Float16* __restrict__ twh,
    const float* __restrict__ tkb, const float* __restrict__ cc,
    const float* __restrict__ aa, _Float16* __restrict__ g) {
  int pt = blockIdx.x & 63, dt = blockIdx.x >> 6;
  int p0 = pt*64, d0 = dt*64;
  int t = threadIdx.x, lane = t & 63, wave = t >> 6;
  int quad = lane >> 4, l15 = lane & 15;
  int wm_ = wave >> 1, wn = wave & 1;
  __shared__ _Float16 la[64*40], lb[64*40];
  int srow = t >> 2, scg = (t & 3) * 8;
  f4 acc[2][2] = {};
  for (int kc = 0; kc < 384; kc += 32) {
    const float* src = fe + (size_t)(p0 + srow)*384 + kc + scg;
    f4 v0 = *(const f4*)src;
    f4 v1 = *(const f4*)(src + 4);
    h8 hv;
    hv[0]=(_Float16)v0[0]; hv[1]=(_Float16)v0[1]; hv[2]=(_Float16)v0[2]; hv[3]=(_Float16)v0[3];
    hv[4]=(_Float16)v1[0]; hv[5]=(_Float16)v1[1]; hv[6]=(_Float16)v1[2]; hv[7]=(_Float16)v1[3];
    *(h8*)&la[srow*40 + scg] = hv;
    *(h8*)&lb[srow*40 + scg] = *(const h8*)&twh[(size_t)(d0 + srow)*384 + kc + scg];
    __syncthreads();
    h8 a0 = *(const h8*)&la[(wm_*32 + l15)*40 + quad*8];
    h8 a1 = *(const h8*)&la[(wm_*32 + 16 + l15)*40 + quad*8];
    h8 b0 = *(const h8*)&lb[(wn*32 + l15)*40 + quad*8];
    h8 b1 = *(const h8*)&lb[(wn*32 + 16 + l15)*40 + quad*8];
    acc[0][0] = MFMA32(a0, b0, acc[0][0]);
    acc[0][1] = MFMA32(a0, b1, acc[0][1]);
    acc[1][0] = MFMA32(a1, b0, acc[1][0]);
    acc[1][1] = MFMA32(a1, b1, acc[1][1]);
    __syncthreads();
  }
  float c0 = cc[0];
  float s1 = (1.0f + 0.5f*aa[0]) / c0;
  #pragma unroll
  for (int i = 0; i < 2; i++)
  #pragma unroll
  for (int j = 0; j < 2; j++) {
    int d  = d0 + wn*32 + j*16 + l15;
    int pl = wm_*32 + i*16 + quad*4;
    float bias = tkb[d];
    h4 hv;
    #pragma unroll
    for (int r = 0; r < 4; r++) {
      float tv = fmaxf(acc[i][j][r] + bias, 0.0f);
      hv[r] = (_Float16)(__cosf(c0*tv) + s1*__sinf(c0*tv));
    }
    *(h4*)&g[(size_t)d*P_N + p0 + pl] = hv;
  }
}

// ---------- GEMM1: 128x128, counted-vmcnt 2-phase + T2 swizzle (R4-best) ----------
__global__ __launch_bounds__(256) void k_gemm1(
    const _Float16* __restrict__ xdw, const _Float16* __restrict__ lwh,
    const float* __restrict__ lnb, _Float16* __restrict__ xs,
    _Float16* __restrict__ zs) {
  int pt = blockIdx.x & 31;
  int rest = blockIdx.x >> 5;
  int dt = rest % 6, b = rest / 6;
  int p0 = pt * 128, d0 = dt * 128;
  int t = threadIdx.x, lane = t & 63, wave = t >> 6;
  int quad = lane >> 4, l15 = lane & 15;
  int wm = wave >> 1, wn = wave & 1;
  __shared__ _Float16 la0[128 * 32], lb0[128 * 32];
  __shared__ _Float16 la1[128 * 32], lb1[128 * 32];
  int s_row = lane >> 2;
  int scol2 = (((lane & 3) ^ (s_row & 3)) * 8);   // T2 pre-swizzled source col
  const _Float16* ga = xdw + ((size_t)b*P_N + p0) * 384 + scol2;
  const _Float16* gb = lwh + (size_t)d0 * 384 + scol2;
  f4 acc[4][4] = {};
  #pragma unroll
  for (int s = 0; s < 2; s++) {
    int seg = wave * 2 + s;
    int row = seg * 16 + s_row;
    gl_lds16(ga + (size_t)row*384, &la0[seg*512 + lane*8]);
    gl_lds16(gb + (size_t)row*384, &lb0[seg*512 + lane*8]);
  }
  #pragma unroll
  for (int kt = 0; kt < 6; kt++) {
    int kc = kt * 64;
    gemm_step(ga, gb, kc + 32,  true,            la0, lb0, la1, lb1, acc);
    gemm_step(ga, gb, kc + 64,  (kc + 64 < 384), la1, lb1, la0, lb0, acc);
  }
  bool isz = (d0 >= 384);
  #pragma unroll
  for (int j = 0; j < 4; j++) {
    int d = d0 + wn*64 + j*16 + l15;
    float bias = lnb[d];
    _Float16* dst = isz ? (zs + ((size_t)b*C_N + (d-384)) * P_N)
                        : (xs + ((size_t)b*C_N + d) * P_N);
    #pragma unroll
    for (int i = 0; i < 4; i++) {
      int p = p0 + wm*64 + i*16 + quad*4;
      h4 hv;
      if (isz) {
        #pragma unroll
        for (int r = 0; r < 4; r++) {
          float v = acc[i][j][r] + bias;
          v = v / (1.0f + __expf(-v));
          hv[r] = (_Float16)v;
        }
      } else {
        #pragma unroll
        for (int r = 0; r < 4; r++) hv[r] = (_Float16)(acc[i][j][r] + bias);
      }
      *(h4*)&dst[p] = hv;
    }
  }
}

// ---------- fused DCT -> gate -> IDCT ----------
__global__ __launch_bounds__(256) void k_dct(
    const _Float16* __restrict__ xs, const _Float16* __restrict__ g,
    const _Float16* __restrict__ wmg, const _Float16* __restrict__ wmtg,
    _Float16* __restrict__ xi) {
  int b = blockIdx.x / 96, cg = blockIdx.x % 96;
  int c0 = cg * 4;
  int t = threadIdx.x, wave = t >> 6, lane = t & 63;
  int quad = lane >> 4, l15 = lane & 15;
  __shared__ _Float16 wm_s[64*72];
  __shared__ _Float16 wmt_s[64*72];
  __shared__ _Float16 pb[4][64*72];
  for (int i = t; i < 512; i += 256) {
    int row = i >> 3, col = (i & 7) * 8;
    *(h8*)&wm_s[row*72 + col]  = *(const h8*)&wmg[row*64 + col];
    *(h8*)&wmt_s[row*72 + col] = *(const h8*)&wmtg[row*64 + col];
  }
  const _Float16* xsb = xs + ((size_t)b*C_N + c0) * P_N;
  for (int i = t; i < 2048; i += 256) {
    int pl = i >> 9, idx = i & 511;
    int p = idx * 8, hh = p >> 6, ww = p & 63;
    *(h8*)&pb[pl][hh*72 + ww] = *(const h8*)&xsb[(size_t)pl*P_N + p];
  }
  __syncthreads();
  h8 aS[4][2], bW[4][2];
  #pragma unroll
  for (int I = 0; I < 4; I++)
  #pragma unroll
  for (int kk = 0; kk < 2; kk++) {
    aS[I][kk] = *(const h8*)&pb[wave][(I*16 + l15)*72 + kk*32 + quad*8];
    bW[I][kk] = *(const h8*)&wm_s[(I*16 + l15)*72 + kk*32 + quad*8];
  }
  h4 t1h[4][4];
  #pragma unroll
  for (int I = 0; I < 4; I++)
  #pragma unroll
  for (int J = 0; J < 4; J++) {
    f4 a = {};
    a = MFMA32(aS[I][0], bW[J][0], a);
    a = MFMA32(aS[I][1], bW[J][1], a);
    t1h[I][J] = to_h4(a);
  }
  __syncthreads();
  // stage gate TRANSPOSED: pb[pl][k*72 + n] via 4x8 register transpose
  const _Float16* gb = g + (size_t)c0 * P_N;
  #pragma unroll
  for (int i = 0; i < 2; i++) {
    int id = t + 256 * i;            // 512 tasks: 4 planes x 16 n-quads x 8 k-groups
    int pl = id >> 7;
    int r7 = id & 127;
    int n4 = (r7 >> 3) * 4;
    int k8 = (r7 & 7) * 8;
    h8 v[4];
    #pragma unroll
    for (int q = 0; q < 4; q++)
      v[q] = *(const h8*)&gb[(size_t)pl*P_N + (n4 + q)*64 + k8];
    #pragma unroll
    for (int e = 0; e < 8; e++) {
      h4 w;
      #pragma unroll
      for (int q = 0; q < 4; q++) w[q] = v[q][e];
      *(h4*)&pb[pl][(k8 + e)*72 + n4] = w;
    }
  }
  __syncthreads();
  f4 t2[4][4] = {};
  #pragma unroll
  for (int I = 0; I < 4; I++)
  #pragma unroll
  for (int K4 = 0; K4 < 4; K4++) {
    h4 af = *(const h4*)&wm_s[(I*16 + l15)*72 + K4*16 + quad*4];
    #pragma unroll
    for (int J = 0; J < 4; J++) t2[I][J] = MFMA16(af, t1h[K4][J], t2[I][J]);
  }
  h4 fh[4][4];
  #pragma unroll
  for (int I = 0; I < 4; I++)
  #pragma unroll
  for (int J = 0; J < 4; J++) {
    h4 gv4 = *(const h4*)&pb[wave][(J*16 + l15)*72 + I*16 + quad*4];
    h4 r;
    #pragma unroll
    for (int rr = 0; rr < 4; rr++)
      r[rr] = (_Float16)(t2[I][J][rr] * (float)gv4[rr]);
    fh[I][J] = r;
  }
  f4 t3[4][4] = {};
  #pragma unroll
  for (int J = 0; J < 4; J++)
  #pragma unroll
  for (int K4 = 0; K4 < 4; K4++) {
    h4 bf = *(const h4*)&wmt_s[(J*16 + l15)*72 + K4*16 + quad*4];
    #pragma unroll
    for (int I = 0; I < 4; I++) t3[I][J] = MFMA16(fh[K4][I], bf, t3[I][J]);
  }
  h4 t3h[4][4];
  #pragma unroll
  for (int I = 0; I < 4; I++)
  #pragma unroll
  for (int J = 0; J < 4; J++) t3h[I][J] = to_h4(t3[I][J]);
  f4 t4[4][4] = {};
  #pragma unroll
  for (int I = 0; I < 4; I++)
  #pragma unroll
  for (int K4 = 0; K4 < 4; K4++) {
    h4 af = *(const h4*)&wmt_s[(I*16 + l15)*72 + K4*16 + quad*4];
    #pragma unroll
    for (int J = 0; J < 4; J++) t4[I][J] = MFMA16(af, t3h[K4][J], t4[I][J]);
  }
  #pragma unroll
  for (int I = 0; I < 4; I++)
  #pragma unroll
  for (int J = 0; J < 4; J++) {
    int w0 = I*16 + quad*4, hq = J*16 + l15;
    *(h4*)&pb[wave][hq*72 + w0] = to_h4(t4[I][J]);
  }
  __syncthreads();
  _Float16* xib = xi + ((size_t)b*C_N + c0) * P_N;
  for (int i = t; i < 2048; i += 256) {
    int pl = i >> 9, idx = i & 511;
    int p = idx * 8, hh = p >> 6, ww = p & 63;
    *(h8*)&xib[(size_t)pl*P_N + p] = *(const h8*)&pb[pl][hh*72 + ww];
  }
}

// ---------- fused LN+silu+GEMM2: xi,zs -> out, 32-px tile, 1024 blocks ----------
// Phase 1 = LN build into ut[32][392]; phase 2 = barrier-free GEMM, A from
// resident LDS, B direct-global (owh 288KB L2-resident). 4 blocks/CU.
__global__ __launch_bounds__(256) void k_fuse(
    const _Float16* __restrict__ xi, const _Float16* __restrict__ zs,
    const float* __restrict__ lng, const float* __restrict__ lnbv,
    const _Float16* __restrict__ owh, const float* __restrict__ ob,
    float* __restrict__ out) {
  int b = blockIdx.x >> 7, pt = blockIdx.x & 127;
  int p0 = pt * 32;
  int t = threadIdx.x;
  __shared__ _Float16 ut[32 * 392];
  __shared__ float red[8][32], red2[8][32];
  __shared__ float muL[32], rsL[32];
  const _Float16* xib = xi + (size_t)b * C_N * P_N;
  // phase 1: xi[c][p] -> ut[px][c], 384 tasks (96 c-quads x 4 px-groups)
  #pragma unroll
  for (int i = 0; i < 2; i++) {
    int id = t + 256 * i;
    if (id < 384) {
      int px0 = (id & 3) * 8;
      int c4 = (id >> 2) * 4;
      h8 v[4];
      #pragma unroll
      for (int q = 0; q < 4; q++)
        v[q] = *(const h8*)&xib[(size_t)(c4 + q) * P_N + p0 + px0];
      #pragma unroll
      for (int e = 0; e < 8; e++) {
        h4 w;
        #pragma unroll
        for (int q = 0; q < 4; q++) w[q] = v[q][e];
        *(h4*)&ut[(px0 + e) * 392 + c4] = w;
      }
    }
  }
  __syncthreads();
  // stats: 8 segs x 48 c each
  int px = t & 31, seg = t >> 5;
  float s = 0.f, ss = 0.f;
  #pragma unroll
  for (int j = 0; j < 6; j++) {
    h8 v = *(const h8*)&ut[px * 392 + seg * 48 + j * 8];
    #pragma unroll
    for (int e = 0; e < 8; e++) { float f = (float)v[e]; s += f; ss += f * f; }
  }
  red[seg][px] = s; red2[seg][px] = ss;
  __syncthreads();
  if (t < 32) {
    float st = 0.f, sst = 0.f;
    #pragma unroll
    for (int sg = 0; sg < 8; sg++) { st += red[sg][t]; sst += red2[sg][t]; }
    float m = st * (1.f/384.f);
    float var = sst * (1.f/384.f) - m * m;
    muL[t] = m; rsL[t] = rsqrtf(var + 1e-5f);
  }
  __syncthreads();
  // phase 3: LN + *silu(z)
  const _Float16* zb = zs + (size_t)b * C_N * P_N;
  #pragma unroll
  for (int i = 0; i < 2; i++) {
    int id = t + 256 * i;
    if (id < 384) {
      int px0 = (id & 3) * 8;
      int c4 = (id >> 2) * 4;
      f4 g4 = *(const f4*)&lng[c4];
      f4 b4 = *(const f4*)&lnbv[c4];
      h8 z[4];
      #pragma unroll
      for (int q = 0; q < 4; q++)
        z[q] = *(const h8*)&zb[(size_t)(c4 + q) * P_N + p0 + px0];
      #pragma unroll
      for (int e = 0; e < 8; e++) {
        int p = px0 + e;
        h4 y = *(const h4*)&ut[p * 392 + c4];
        float mu = muL[p], rs = rsL[p];
        #pragma unroll
        for (int q = 0; q < 4; q++) {
          float f = ((float)y[q] - mu) * rs * g4[q] + b4[q];
          y[q] = (_Float16)(f * (float)z[q][e]);
        }
        *(h4*)&ut[p * 392 + c4] = y;
      }
    }
  }
  __syncthreads();
  // phase 2: barrier-free GEMM. wave owns 96 d-cols; 32 px (2 x 16).
  int lane = t & 63, wave = t >> 6;
  int quad = lane >> 4, l15 = lane & 15;
  int n0 = wave * 96;
  f4 acc[2][6] = {};
  const _Float16* bw = owh + (size_t)(n0 + l15) * 384 + quad * 8;
  #pragma unroll
  for (int kc = 0; kc < 384; kc += 32) {
    h8 af[2], bf[6];
    #pragma unroll
    for (int i = 0; i < 2; i++)
      af[i] = *(const h8*)&ut[(i*16 + l15) * 392 + kc + quad*8];
    #pragma unroll
    for (int j = 0; j < 6; j++)
      bf[j] = *(const h8*)&bw[(size_t)(j*16) * 384 + kc];
    #pragma unroll
    for (int i = 0; i < 2; i++)
    #pragma unroll
    for (int j = 0; j < 6; j++)
      acc[i][j] = MFMA32(af[i], bf[j], acc[i][j]);
  }
  #pragma unroll
  for (int j = 0; j < 6; j++) {
    int d = n0 + j*16 + l15;
    float bias = ob[d];
    float* op = out + ((size_t)b*C_N + d) * P_N + p0;
    #pragma unroll
    for (int i = 0; i < 2; i++) {
      f4 v;
      #pragma unroll
      for (int r = 0; r < 4; r++) v[r] = acc[i][j][r] + bias;
      *(f4*)&op[i*16 + quad*4] = v;
    }
  }
}

extern "C" void kernel_launch(void* const* d_in, const int* in_sizes, int n_in,
                              void* d_out, int out_size, void* d_ws, size_t ws_size,
                              hipStream_t stream) {
  (void)in_sizes; (void)n_in; (void)out_size; (void)ws_size;
  const float* x    = (const float*)d_in[0];
  const float* fe   = (const float*)d_in[1];
  const float* dww  = (const float*)d_in[2];
  const float* dwb  = (const float*)d_in[3];
  const float* linw = (const float*)d_in[4];
  const float* linb = (const float*)d_in[5];
  const float* tokw = (const float*)d_in[6];
  const float* tokb = (const float*)d_in[7];
  const float* cc   = (const float*)d_in[8];
  const float* aa   = (const float*)d_in[9];
  const float* lng  = (const float*)d_in[10];
  const float* lnbv = (const float*)d_in[11];
  const float* outw = (const float*)d_in[12];
  const float* outb = (const float*)d_in[13];
  float* out = (float*)d_out;

  char* ws = (char*)d_ws;
  size_t off = 0;
  auto alloc = [&](size_t bytes) -> void* {
    void* p = ws + off;
    off += (bytes + 255) & ~(size_t)255;
    return p;
  };
  _Float16* lwh  = (_Float16*)alloc((size_t)768*384*2);
  _Float16* twh  = (_Float16*)alloc((size_t)384*384*2);
  _Float16* owh  = (_Float16*)alloc((size_t)384*384*2);
  _Float16* wmg  = (_Float16*)alloc((size_t)64*64*2);
  _Float16* wmtg = (_Float16*)alloc((size_t)64*64*2);
  _Float16* xdw  = (_Float16*)alloc((size_t)B_N*P_N*C_N*2);
  _Float16* xs   = (_Float16*)alloc((size_t)B_N*C_N*P_N*2);
  _Float16* zs   = (_Float16*)alloc((size_t)B_N*C_N*P_N*2);
  _Float16* gg   = (_Float16*)alloc((size_t)C_N*P_N*2);
  _Float16* xi   = xdw;   // xdw dead after k_gemm1

  k_setup<<<1152, 256, 0, stream>>>(linw, tokw, outw, lwh, twh, owh, wmg, wmtg);
  k_dwconv<<<768, 256, 0, stream>>>(x, dww, dwb, xdw);
  k_gate<<<384, 256, 0, stream>>>(fe, twh, tokb, cc, aa, gg);
  k_gemm1<<<1536, 256, 0, stream>>>(xdw, lwh, linb, xs, zs);
  k_dct<<<768, 256, 0, stream>>>(xs, gg, wmg, wmtg, xi);
  k_fuse<<<1024, 256, 0, stream>>>(xi, zs, lng, lnbv, owh, outb, out);
}

// Round 14
// 231.163 us; speedup vs baseline: 1.0789x; 1.0789x over previous
//
#include <hip/hip_runtime.h>

typedef _Float16 h2 __attribute__((ext_vector_type(2)));
typedef _Float16 h4 __attribute__((ext_vector_type(4)));
typedef _Float16 h8 __attribute__((ext_vector_type(8)));
typedef float    f4 __attribute__((ext_vector_type(4)));

#define MFMA32(a,b,c) __builtin_amdgcn_mfma_f32_16x16x32_f16((a),(b),(c),0,0,0)
#define MFMA16(a,b,c) __builtin_amdgcn_mfma_f32_16x16x16f16((a),(b),(c),0,0,0)

#define B_N 8
#define C_N 384
#define P_N 4096
#define PI_F 3.14159265358979323846f

__device__ __forceinline__ h4 to_h4(f4 v) {
  h4 r; r[0]=(_Float16)v[0]; r[1]=(_Float16)v[1]; r[2]=(_Float16)v[2]; r[3]=(_Float16)v[3];
  return r;
}

// async global->LDS, 16B per lane; LDS dest = wave-uniform base + lane*16 (m97/m104)
__device__ __forceinline__ void gl_lds16(const _Float16* g, _Float16* l) {
  __builtin_amdgcn_global_load_lds(
      (const __attribute__((address_space(1))) void*)g,
      (__attribute__((address_space(3))) void*)l, 16, 0, 0);
}

// one K-step: counted vmcnt + raw barriers (T3/T4 minimum form), T2 chunk-XOR
// swizzle (pre-swizzled global src, swizzled ds_read; LDS dest linear).
__device__ __forceinline__ void gemm_step(
    const _Float16* __restrict__ ga, const _Float16* __restrict__ gb,
    int kcn, bool pref,
    _Float16* laC, _Float16* lbC, _Float16* laN, _Float16* lbN,
    f4 (&acc)[4][4]) {
  int t = threadIdx.x, lane = t & 63, wave = t >> 6;
  int quad = lane >> 4, l15 = lane & 15;
  int wm = wave >> 1, wn = wave & 1;
  int s_row = lane >> 2;
  if (pref) {
    #pragma unroll
    for (int s = 0; s < 2; s++) {
      int seg = wave * 2 + s;
      int row = seg * 16 + s_row;
      gl_lds16(ga + (size_t)row*384 + kcn, &laN[seg*512 + lane*8]);
      gl_lds16(gb + (size_t)row*384 + kcn, &lbN[seg*512 + lane*8]);
    }
    // wait own PREVIOUS step's 4 staging loads (oldest); 4 new stay in flight
    asm volatile("s_waitcnt vmcnt(4)" ::: "memory");
  } else {
    asm volatile("s_waitcnt vmcnt(0)" ::: "memory");
  }
  __builtin_amdgcn_s_barrier();          // all waves: current buffers staged
  asm volatile("" ::: "memory");
  h8 af[4], bf[4];
  int sq = (quad ^ (l15 & 3)) * 8;       // read-side swizzle (row&3 == l15&3)
  #pragma unroll
  for (int i = 0; i < 4; i++) {
    af[i] = *(const h8*)&laC[(wm*64 + i*16 + l15)*32 + sq];
    bf[i] = *(const h8*)&lbC[(wn*64 + i*16 + l15)*32 + sq];
  }
  asm volatile("s_waitcnt lgkmcnt(0)" ::: "memory");
  __builtin_amdgcn_s_barrier();          // all waves: reads done -> overwrite ok
  asm volatile("" ::: "memory");
  #pragma unroll
  for (int i = 0; i < 4; i++)
  #pragma unroll
  for (int j = 0; j < 4; j++)
    acc[i][j] = MFMA32(af[i], bf[j], acc[i][j]);
}

// ---------- setup: fp32->fp16 weights + DCT matrices ----------
__global__ __launch_bounds__(256) void k_setup(
    const float* __restrict__ lin_w, const float* __restrict__ tok_w,
    const float* __restrict__ out_w, _Float16* __restrict__ lwh,
    _Float16* __restrict__ twh, _Float16* __restrict__ owh,
    _Float16* __restrict__ wmg, _Float16* __restrict__ wmtg) {
  int t = blockIdx.x * 256 + threadIdx.x;
  if (t < 768*384) lwh[t] = (_Float16)lin_w[t];
  if (t < 384*384) { twh[t] = (_Float16)tok_w[t]; owh[t] = (_Float16)out_w[t]; }
  if (t < 4096) {
    int n = t >> 6, h = t & 63;
    float v = cosf((float)n * ((float)h + 0.5f) * (PI_F / 64.0f)) * 0.1767766952966369f;
    if (n == 0) v *= 0.7071067811865476f;
    wmg[n*64 + h]  = (_Float16)v;
    wmtg[h*64 + n] = (_Float16)v;
  }
}

// ---------- depthwise 3x3 conv, h-strip of 4 rows -> xdw[b][p][c] fp16 ----------
__global__ __launch_bounds__(256) void k_dwconv(
    const float* __restrict__ x, const float* __restrict__ dww,
    const float* __restrict__ dwb, _Float16* __restrict__ xdw) {
  int blk = blockIdx.x;
  int hs = blk & 15;            // 16 strips of 4 h-rows
  int rest = blk >> 4;
  int cgi = rest % 6;
  int b = rest / 6;
  int c0 = cgi * 64;
  int h0 = hs * 4;
  int t = threadIdx.x;
  __shared__ float wsm[576];
  __shared__ float bsm[64];
  __shared__ _Float16 buf[4][64 * 68];
  for (int i = t; i < 576; i += 256) wsm[i] = dww[c0*9 + i];
  if (t < 64) bsm[t] = dwb[c0 + t];
  __syncthreads();
  int lane = t & 63;
  int wslot = lane & 15, w4 = wslot * 4;
  int cs = t >> 4;              // 16 slots x 4 channels
  bool wlo = (wslot == 0), whi = (wslot == 15);
  int lm = (lane - 1) & 63, lp = (lane + 1) & 63;
  const float* xb = x + (size_t)b * C_N * P_N + w4;
  f4 prev[4], cur[4];
  float pL[4], pR[4], cL[4], cR[4];
  #pragma unroll
  for (int q = 0; q < 4; q++) {
    const float* xc = xb + (size_t)(c0 + cs*4 + q) * P_N;
    prev[q] = (h0 > 0) ? *(const f4*)(xc + (h0-1)*64) : f4{0.f,0.f,0.f,0.f};
    cur[q]  = *(const f4*)(xc + h0*64);
    pL[q] = __shfl(prev[q][3], lm, 64); pR[q] = __shfl(prev[q][0], lp, 64);
    cL[q] = __shfl(cur[q][3],  lm, 64); cR[q] = __shfl(cur[q][0],  lp, 64);
    if (wlo) { pL[q] = 0.f; cL[q] = 0.f; }
    if (whi) { pR[q] = 0.f; cR[q] = 0.f; }
  }
  #pragma unroll
  for (int r = 0; r < 4; r++) {
    int h = h0 + r;
    float o[4][4];
    #pragma unroll
    for (int q = 0; q < 4; q++) {
      int lc = cs*4 + q;
      const float* xc = xb + (size_t)(c0 + lc) * P_N;
      f4 nxt = (h < 63) ? *(const f4*)(xc + (h+1)*64) : f4{0.f,0.f,0.f,0.f};
      float nL = __shfl(nxt[3], lm, 64), nR = __shfl(nxt[0], lp, 64);
      if (wlo) nL = 0.f;
      if (whi) nR = 0.f;
      float k0=wsm[lc*9+0],k1=wsm[lc*9+1],k2=wsm[lc*9+2];
      float k3=wsm[lc*9+3],k4=wsm[lc*9+4],k5=wsm[lc*9+5];
      float k6=wsm[lc*9+6],k7=wsm[lc*9+7],k8=wsm[lc*9+8];
      float bias = bsm[lc];
      #pragma unroll
      for (int e = 0; e < 4; e++) {
        float tl = (e > 0) ? prev[q][e-1] : pL[q];
        float tr = (e < 3) ? prev[q][e+1] : pR[q];
        float ml = (e > 0) ? cur[q][e-1]  : cL[q];
        float mr = (e < 3) ? cur[q][e+1]  : cR[q];
        float bl = (e > 0) ? nxt[e-1]     : nL;
        float br = (e < 3) ? nxt[e+1]     : nR;
        float acc = bias;
        acc += k0*tl + k1*prev[q][e] + k2*tr;
        acc += k3*ml + k4*cur[q][e]  + k5*mr;
        acc += k6*bl + k7*nxt[e]     + k8*br;
        o[q][e] = acc;
      }
      prev[q] = cur[q]; pL[q] = cL[q]; pR[q] = cR[q];
      cur[q] = nxt;     cL[q] = nL;    cR[q] = nR;
    }
    #pragma unroll
    for (int e = 0; e < 4; e++) {
      h4 hv;
      #pragma unroll
      for (int q = 0; q < 4; q++) hv[q] = (_Float16)o[q][e];
      *(h4*)&buf[r][(w4 + e) * 68 + cs * 4] = hv;
    }
  }
  __syncthreads();
  #pragma unroll
  for (int r = 0; r < 4; r++) {
    _Float16* op = xdw + ((size_t)b*P_N + (h0 + r)*64) * C_N + c0;
    #pragma unroll
    for (int i = 0; i < 4; i++) {
      int flat = (t + 256*i) * 4;
      int pix = flat >> 6, cl = flat & 63;
      *(h4*)&op[(size_t)pix*C_N + cl] = *(const h4*)&buf[r][pix*68 + cl];
    }
  }
}

// ---------- tok GEMM + trig gate ----------
__global__ __launch_bounds__(256) void k_gate(
    const float* __restrict__ fe, const _Float16* __restrict__ twh,
    const float* __restrict__ tkb, const float* __restrict__ cc,
    const float* __restrict__ aa, _Float16* __restrict__ g) {
  int pt = blockIdx.x & 63, dt = blockIdx.x >> 6;
  int p0 = pt*64, d0 = dt*64;
  int t = threadIdx.x, lane = t & 63, wave = t >> 6;
  int quad = lane >> 4, l15 = lane & 15;
  int wm_ = wave >> 1, wn = wave & 1;
  __shared__ _Float16 la[64*40], lb[64*40];
  int srow = t >> 2, scg = (t & 3) * 8;
  f4 acc[2][2] = {};
  for (int kc = 0; kc < 384; kc += 32) {
    const float* src = fe + (size_t)(p0 + srow)*384 + kc + scg;
    f4 v0 = *(const f4*)src;
    f4 v1 = *(const f4*)(src + 4);
    h8 hv;
    hv[0]=(_Float16)v0[0]; hv[1]=(_Float16)v0[1]; hv[2]=(_Float16)v0[2]; hv[3]=(_Float16)v0[3];
    hv[4]=(_Float16)v1[0]; hv[5]=(_Float16)v1[1]; hv[6]=(_Float16)v1[2]; hv[7]=(_Float16)v1[3];
    *(h8*)&la[srow*40 + scg] = hv;
    *(h8*)&lb[srow*40 + scg] = *(const h8*)&twh[(size_t)(d0 + srow)*384 + kc + scg];
    __syncthreads();
    h8 a0 = *(const h8*)&la[(wm_*32 + l15)*40 + quad*8];
    h8 a1 = *(const h8*)&la[(wm_*32 + 16 + l15)*40 + quad*8];
    h8 b0 = *(const h8*)&lb[(wn*32 + l15)*40 + quad*8];
    h8 b1 = *(const h8*)&lb[(wn*32 + 16 + l15)*40 + quad*8];
    acc[0][0] = MFMA32(a0, b0, acc[0][0]);
    acc[0][1] = MFMA32(a0, b1, acc[0][1]);
    acc[1][0] = MFMA32(a1, b0, acc[1][0]);
    acc[1][1] = MFMA32(a1, b1, acc[1][1]);
    __syncthreads();
  }
  float c0 = cc[0];
  float s1 = (1.0f + 0.5f*aa[0]) / c0;
  #pragma unroll
  for (int i = 0; i < 2; i++)
  #pragma unroll
  for (int j = 0; j < 2; j++) {
    int d  = d0 + wn*32 + j*16 + l15;
    int pl = wm_*32 + i*16 + quad*4;
    float bias = tkb[d];
    h4 hv;
    #pragma unroll
    for (int r = 0; r < 4; r++) {
      float tv = fmaxf(acc[i][j][r] + bias, 0.0f);
      hv[r] = (_Float16)(__cosf(c0*tv) + s1*__sinf(c0*tv));
    }
    *(h4*)&g[(size_t)d*P_N + p0 + pl] = hv;
  }
}

// ---------- GEMM1: 128x128, counted-vmcnt 2-phase + T2 swizzle (R4-best) ----------
__global__ __launch_bounds__(256) void k_gemm1(
    const _Float16* __restrict__ xdw, const _Float16* __restrict__ lwh,
    const float* __restrict__ lnb, _Float16* __restrict__ xs,
    _Float16* __restrict__ zs) {
  int pt = blockIdx.x & 31;
  int rest = blockIdx.x >> 5;
  int dt = rest % 6, b = rest / 6;
  int p0 = pt * 128, d0 = dt * 128;
  int t = threadIdx.x, lane = t & 63, wave = t >> 6;
  int quad = lane >> 4, l15 = lane & 15;
  int wm = wave >> 1, wn = wave & 1;
  __shared__ _Float16 la0[128 * 32], lb0[128 * 32];
  __shared__ _Float16 la1[128 * 32], lb1[128 * 32];
  int s_row = lane >> 2;
  int scol2 = (((lane & 3) ^ (s_row & 3)) * 8);   // T2 pre-swizzled source col
  const _Float16* ga = xdw + ((size_t)b*P_N + p0) * 384 + scol2;
  const _Float16* gb = lwh + (size_t)d0 * 384 + scol2;
  f4 acc[4][4] = {};
  #pragma unroll
  for (int s = 0; s < 2; s++) {
    int seg = wave * 2 + s;
    int row = seg * 16 + s_row;
    gl_lds16(ga + (size_t)row*384, &la0[seg*512 + lane*8]);
    gl_lds16(gb + (size_t)row*384, &lb0[seg*512 + lane*8]);
  }
  #pragma unroll
  for (int kt = 0; kt < 6; kt++) {
    int kc = kt * 64;
    gemm_step(ga, gb, kc + 32,  true,            la0, lb0, la1, lb1, acc);
    gemm_step(ga, gb, kc + 64,  (kc + 64 < 384), la1, lb1, la0, lb0, acc);
  }
  bool isz = (d0 >= 384);
  #pragma unroll
  for (int j = 0; j < 4; j++) {
    int d = d0 + wn*64 + j*16 + l15;
    float bias = lnb[d];
    _Float16* dst = isz ? (zs + ((size_t)b*C_N + (d-384)) * P_N)
                        : (xs + ((size_t)b*C_N + d) * P_N);
    #pragma unroll
    for (int i = 0; i < 4; i++) {
      int p = p0 + wm*64 + i*16 + quad*4;
      h4 hv;
      if (isz) {
        #pragma unroll
        for (int r = 0; r < 4; r++) {
          float v = acc[i][j][r] + bias;
          v = v / (1.0f + __expf(-v));
          hv[r] = (_Float16)v;
        }
      } else {
        #pragma unroll
        for (int r = 0; r < 4; r++) hv[r] = (_Float16)(acc[i][j][r] + bias);
      }
      *(h4*)&dst[p] = hv;
    }
  }
}

// ---------- fused DCT -> gate -> IDCT ----------
__global__ __launch_bounds__(256) void k_dct(
    const _Float16* __restrict__ xs, const _Float16* __restrict__ g,
    const _Float16* __restrict__ wmg, const _Float16* __restrict__ wmtg,
    _Float16* __restrict__ xi) {
  int b = blockIdx.x / 96, cg = blockIdx.x % 96;
  int c0 = cg * 4;
  int t = threadIdx.x, wave = t >> 6, lane = t & 63;
  int quad = lane >> 4, l15 = lane & 15;
  __shared__ _Float16 wm_s[64*72];
  __shared__ _Float16 wmt_s[64*72];
  __shared__ _Float16 pb[4][64*72];
  for (int i = t; i < 512; i += 256) {
    int row = i >> 3, col = (i & 7) * 8;
    *(h8*)&wm_s[row*72 + col]  = *(const h8*)&wmg[row*64 + col];
    *(h8*)&wmt_s[row*72 + col] = *(const h8*)&wmtg[row*64 + col];
  }
  const _Float16* xsb = xs + ((size_t)b*C_N + c0) * P_N;
  for (int i = t; i < 2048; i += 256) {
    int pl = i >> 9, idx = i & 511;
    int p = idx * 8, hh = p >> 6, ww = p & 63;
    *(h8*)&pb[pl][hh*72 + ww] = *(const h8*)&xsb[(size_t)pl*P_N + p];
  }
  __syncthreads();
  h8 aS[4][2], bW[4][2];
  #pragma unroll
  for (int I = 0; I < 4; I++)
  #pragma unroll
  for (int kk = 0; kk < 2; kk++) {
    aS[I][kk] = *(const h8*)&pb[wave][(I*16 + l15)*72 + kk*32 + quad*8];
    bW[I][kk] = *(const h8*)&wm_s[(I*16 + l15)*72 + kk*32 + quad*8];
  }
  h4 t1h[4][4];
  #pragma unroll
  for (int I = 0; I < 4; I++)
  #pragma unroll
  for (int J = 0; J < 4; J++) {
    f4 a = {};
    a = MFMA32(aS[I][0], bW[J][0], a);
    a = MFMA32(aS[I][1], bW[J][1], a);
    t1h[I][J] = to_h4(a);
  }
  __syncthreads();
  // stage gate TRANSPOSED: pb[pl][k*72 + n] via 4x8 register transpose
  const _Float16* gb = g + (size_t)c0 * P_N;
  #pragma unroll
  for (int i = 0; i < 2; i++) {
    int id = t + 256 * i;            // 512 tasks: 4 planes x 16 n-quads x 8 k-groups
    int pl = id >> 7;
    int r7 = id & 127;
    int n4 = (r7 >> 3) * 4;
    int k8 = (r7 & 7) * 8;
    h8 v[4];
    #pragma unroll
    for (int q = 0; q < 4; q++)
      v[q] = *(const h8*)&gb[(size_t)pl*P_N + (n4 + q)*64 + k8];
    #pragma unroll
    for (int e = 0; e < 8; e++) {
      h4 w;
      #pragma unroll
      for (int q = 0; q < 4; q++) w[q] = v[q][e];
      *(h4*)&pb[pl][(k8 + e)*72 + n4] = w;
    }
  }
  __syncthreads();
  f4 t2[4][4] = {};
  #pragma unroll
  for (int I = 0; I < 4; I++)
  #pragma unroll
  for (int K4 = 0; K4 < 4; K4++) {
    h4 af = *(const h4*)&wm_s[(I*16 + l15)*72 + K4*16 + quad*4];
    #pragma unroll
    for (int J = 0; J < 4; J++) t2[I][J] = MFMA16(af, t1h[K4][J], t2[I][J]);
  }
  h4 fh[4][4];
  #pragma unroll
  for (int I = 0; I < 4; I++)
  #pragma unroll
  for (int J = 0; J < 4; J++) {
    h4 gv4 = *(const h4*)&pb[wave][(J*16 + l15)*72 + I*16 + quad*4];
    h4 r;
    #pragma unroll
    for (int rr = 0; rr < 4; rr++)
      r[rr] = (_Float16)(t2[I][J][rr] * (float)gv4[rr]);
    fh[I][J] = r;
  }
  f4 t3[4][4] = {};
  #pragma unroll
  for (int J = 0; J < 4; J++)
  #pragma unroll
  for (int K4 = 0; K4 < 4; K4++) {
    h4 bf = *(const h4*)&wmt_s[(J*16 + l15)*72 + K4*16 + quad*4];
    #pragma unroll
    for (int I = 0; I < 4; I++) t3[I][J] = MFMA16(fh[K4][I], bf, t3[I][J]);
  }
  h4 t3h[4][4];
  #pragma unroll
  for (int I = 0; I < 4; I++)
  #pragma unroll
  for (int J = 0; J < 4; J++) t3h[I][J] = to_h4(t3[I][J]);
  f4 t4[4][4] = {};
  #pragma unroll
  for (int I = 0; I < 4; I++)
  #pragma unroll
  for (int K4 = 0; K4 < 4; K4++) {
    h4 af = *(const h4*)&wmt_s[(I*16 + l15)*72 + K4*16 + quad*4];
    #pragma unroll
    for (int J = 0; J < 4; J++) t4[I][J] = MFMA16(af, t3h[K4][J], t4[I][J]);
  }
  #pragma unroll
  for (int I = 0; I < 4; I++)
  #pragma unroll
  for (int J = 0; J < 4; J++) {
    int w0 = I*16 + quad*4, hq = J*16 + l15;
    *(h4*)&pb[wave][hq*72 + w0] = to_h4(t4[I][J]);
  }
  __syncthreads();
  _Float16* xib = xi + ((size_t)b*C_N + c0) * P_N;
  for (int i = t; i < 2048; i += 256) {
    int pl = i >> 9, idx = i & 511;
    int p = idx * 8, hh = p >> 6, ww = p & 63;
    *(h8*)&xib[(size_t)pl*P_N + p] = *(const h8*)&pb[pl][hh*72 + ww];
  }
}

// ---------- fused LN+silu+GEMM2: 64-px tile, 8 waves (48 d-cols each) ----------
// Same B-traffic as R12 (512 blocks), 2x the wave pool for phase-2 latency.
__global__ __launch_bounds__(512) void k_fuse(
    const _Float16* __restrict__ xi, const _Float16* __restrict__ zs,
    const float* __restrict__ lng, const float* __restrict__ lnbv,
    const _Float16* __restrict__ owh, const float* __restrict__ ob,
    float* __restrict__ out) {
  int b = blockIdx.x >> 6, pt = blockIdx.x & 63;
  int p0 = pt * 64;
  int t = threadIdx.x;
  __shared__ _Float16 ut[64 * 392];
  __shared__ float red[8][64], red2[8][64];
  __shared__ float muL[64], rsL[64];
  const _Float16* xib = xi + (size_t)b * C_N * P_N;
  // phase 1: xi[c][p] -> ut[px][c], 768 tasks (96 c-quads x 8 px-groups)
  #pragma unroll
  for (int i = 0; i < 2; i++) {
    int id = t + 512 * i;
    if (id < 768) {
      int px0 = (id & 7) * 8;
      int c4 = (id >> 3) * 4;
      h8 v[4];
      #pragma unroll
      for (int q = 0; q < 4; q++)
        v[q] = *(const h8*)&xib[(size_t)(c4 + q) * P_N + p0 + px0];
      #pragma unroll
      for (int e = 0; e < 8; e++) {
        h4 w;
        #pragma unroll
        for (int q = 0; q < 4; q++) w[q] = v[q][e];
        *(h4*)&ut[(px0 + e) * 392 + c4] = w;
      }
    }
  }
  __syncthreads();
  // stats: 8 segs x 48 c each
  int px = t & 63, seg = t >> 6;
  float s = 0.f, ss = 0.f;
  #pragma unroll
  for (int j = 0; j < 6; j++) {
    h8 v = *(const h8*)&ut[px * 392 + seg * 48 + j * 8];
    #pragma unroll
    for (int e = 0; e < 8; e++) { float f = (float)v[e]; s += f; ss += f * f; }
  }
  red[seg][px] = s; red2[seg][px] = ss;
  __syncthreads();
  if (t < 64) {
    float st = 0.f, sst = 0.f;
    #pragma unroll
    for (int sg = 0; sg < 8; sg++) { st += red[sg][t]; sst += red2[sg][t]; }
    float m = st * (1.f/384.f);
    float var = sst * (1.f/384.f) - m * m;
    muL[t] = m; rsL[t] = rsqrtf(var + 1e-5f);
  }
  __syncthreads();
  // phase 3: LN + *silu(z)
  const _Float16* zb = zs + (size_t)b * C_N * P_N;
  #pragma unroll
  for (int i = 0; i < 2; i++) {
    int id = t + 512 * i;
    if (id < 768) {
      int px0 = (id & 7) * 8;
      int c4 = (id >> 3) * 4;
      f4 g4 = *(const f4*)&lng[c4];
      f4 b4 = *(const f4*)&lnbv[c4];
      h8 z[4];
      #pragma unroll
      for (int q = 0; q < 4; q++)
        z[q] = *(const h8*)&zb[(size_t)(c4 + q) * P_N + p0 + px0];
      #pragma unroll
      for (int e = 0; e < 8; e++) {
        int p = px0 + e;
        h4 y = *(const h4*)&ut[p * 392 + c4];
        float mu = muL[p], rs = rsL[p];
        #pragma unroll
        for (int q = 0; q < 4; q++) {
          float f = ((float)y[q] - mu) * rs * g4[q] + b4[q];
          y[q] = (_Float16)(f * (float)z[q][e]);
        }
        *(h4*)&ut[p * 392 + c4] = y;
      }
    }
  }
  __syncthreads();
  // phase 2: barrier-free GEMM. 8 waves x 48 d-cols; 64 px (4 x 16) each.
  int lane = t & 63, wave = t >> 6;
  int quad = lane >> 4, l15 = lane & 15;
  int n0 = wave * 48;
  f4 acc[4][3] = {};
  const _Float16* bw = owh + (size_t)(n0 + l15) * 384 + quad * 8;
  #pragma unroll
  for (int kc = 0; kc < 384; kc += 32) {
    h8 af[4], bf[3];
    #pragma unroll
    for (int i = 0; i < 4; i++)
      af[i] = *(const h8*)&ut[(i*16 + l15) * 392 + kc + quad*8];
    #pragma unroll
    for (int j = 0; j < 3; j++)
      bf[j] = *(const h8*)&bw[(size_t)(j*16) * 384 + kc];
    #pragma unroll
    for (int i = 0; i < 4; i++)
    #pragma unroll
    for (int j = 0; j < 3; j++)
      acc[i][j] = MFMA32(af[i], bf[j], acc[i][j]);
  }
  #pragma unroll
  for (int j = 0; j < 3; j++) {
    int d = n0 + j*16 + l15;
    float bias = ob[d];
    float* op = out + ((size_t)b*C_N + d) * P_N + p0;
    #pragma unroll
    for (int i = 0; i < 4; i++) {
      f4 v;
      #pragma unroll
      for (int r = 0; r < 4; r++) v[r] = acc[i][j][r] + bias;
      *(f4*)&op[i*16 + quad*4] = v;
    }
  }
}

extern "C" void kernel_launch(void* const* d_in, const int* in_sizes, int n_in,
                              void* d_out, int out_size, void* d_ws, size_t ws_size,
                              hipStream_t stream) {
  (void)in_sizes; (void)n_in; (void)out_size; (void)ws_size;
  const float* x    = (const float*)d_in[0];
  const float* fe   = (const float*)d_in[1];
  const float* dww  = (const float*)d_in[2];
  const float* dwb  = (const float*)d_in[3];
  const float* linw = (const float*)d_in[4];
  const float* linb = (const float*)d_in[5];
  const float* tokw = (const float*)d_in[6];
  const float* tokb = (const float*)d_in[7];
  const float* cc   = (const float*)d_in[8];
  const float* aa   = (const float*)d_in[9];
  const float* lng  = (const float*)d_in[10];
  const float* lnbv = (const float*)d_in[11];
  const float* outw = (const float*)d_in[12];
  const float* outb = (const float*)d_in[13];
  float* out = (float*)d_out;

  char* ws = (char*)d_ws;
  size_t off = 0;
  auto alloc = [&](size_t bytes) -> void* {
    void* p = ws + off;
    off += (bytes + 255) & ~(size_t)255;
    return p;
  };
  _Float16* lwh  = (_Float16*)alloc((size_t)768*384*2);
  _Float16* twh  = (_Float16*)alloc((size_t)384*384*2);
  _Float16* owh  = (_Float16*)alloc((size_t)384*384*2);
  _Float16* wmg  = (_Float16*)alloc((size_t)64*64*2);
  _Float16* wmtg = (_Float16*)alloc((size_t)64*64*2);
  _Float16* xdw  = (_Float16*)alloc((size_t)B_N*P_N*C_N*2);
  _Float16* xs   = (_Float16*)alloc((size_t)B_N*C_N*P_N*2);
  _Float16* zs   = (_Float16*)alloc((size_t)B_N*C_N*P_N*2);
  _Float16* gg   = (_Float16*)alloc((size_t)C_N*P_N*2);
  _Float16* xi   = xdw;   // xdw dead after k_gemm1

  k_setup<<<1152, 256, 0, stream>>>(linw, tokw, outw, lwh, twh, owh, wmg, wmtg);
  k_dwconv<<<768, 256, 0, stream>>>(x, dww, dwb, xdw);
  k_gate<<<384, 256, 0, stream>>>(fe, twh, tokb, cc, aa, gg);
  k_gemm1<<<1536, 256, 0, stream>>>(xdw, lwh, linb, xs, zs);
  k_dct<<<768, 256, 0, stream>>>(xs, gg, wmg, wmtg, xi);
  k_fuse<<<512, 512, 0, stream>>>(xi, zs, lng, lnbv, owh, outb, out);
}

// Round 15
// 228.802 us; speedup vs baseline: 1.0901x; 1.0103x over previous
//
#include <hip/hip_runtime.h>

typedef _Float16 h2 __attribute__((ext_vector_type(2)));
typedef _Float16 h4 __attribute__((ext_vector_type(4)));
typedef _Float16 h8 __attribute__((ext_vector_type(8)));
typedef float    f4 __attribute__((ext_vector_type(4)));

#define MFMA32(a,b,c) __builtin_amdgcn_mfma_f32_16x16x32_f16((a),(b),(c),0,0,0)
#define MFMA16(a,b,c) __builtin_amdgcn_mfma_f32_16x16x16f16((a),(b),(c),0,0,0)

#define B_N 8
#define C_N 384
#define P_N 4096
#define PI_F 3.14159265358979323846f

__device__ __forceinline__ h4 to_h4(f4 v) {
  h4 r; r[0]=(_Float16)v[0]; r[1]=(_Float16)v[1]; r[2]=(_Float16)v[2]; r[3]=(_Float16)v[3];
  return r;
}

// async global->LDS, 16B per lane; LDS dest = wave-uniform base + lane*16 (m97/m104)
__device__ __forceinline__ void gl_lds16(const _Float16* g, _Float16* l) {
  __builtin_amdgcn_global_load_lds(
      (const __attribute__((address_space(1))) void*)g,
      (__attribute__((address_space(3))) void*)l, 16, 0, 0);
}

// one K-step: counted vmcnt + raw barriers (T3/T4 minimum form), T2 chunk-XOR
// swizzle (pre-swizzled global src, swizzled ds_read; LDS dest linear).
__device__ __forceinline__ void gemm_step(
    const _Float16* __restrict__ ga, const _Float16* __restrict__ gb,
    int kcn, bool pref,
    _Float16* laC, _Float16* lbC, _Float16* laN, _Float16* lbN,
    f4 (&acc)[4][4]) {
  int t = threadIdx.x, lane = t & 63, wave = t >> 6;
  int quad = lane >> 4, l15 = lane & 15;
  int wm = wave >> 1, wn = wave & 1;
  int s_row = lane >> 2;
  if (pref) {
    #pragma unroll
    for (int s = 0; s < 2; s++) {
      int seg = wave * 2 + s;
      int row = seg * 16 + s_row;
      gl_lds16(ga + (size_t)row*384 + kcn, &laN[seg*512 + lane*8]);
      gl_lds16(gb + (size_t)row*384 + kcn, &lbN[seg*512 + lane*8]);
    }
    // wait own PREVIOUS step's 4 staging loads (oldest); 4 new stay in flight
    asm volatile("s_waitcnt vmcnt(4)" ::: "memory");
  } else {
    asm volatile("s_waitcnt vmcnt(0)" ::: "memory");
  }
  __builtin_amdgcn_s_barrier();          // all waves: current buffers staged
  asm volatile("" ::: "memory");
  h8 af[4], bf[4];
  int sq = (quad ^ (l15 & 3)) * 8;       // read-side swizzle (row&3 == l15&3)
  #pragma unroll
  for (int i = 0; i < 4; i++) {
    af[i] = *(const h8*)&laC[(wm*64 + i*16 + l15)*32 + sq];
    bf[i] = *(const h8*)&lbC[(wn*64 + i*16 + l15)*32 + sq];
  }
  asm volatile("s_waitcnt lgkmcnt(0)" ::: "memory");
  __builtin_amdgcn_s_barrier();          // all waves: reads done -> overwrite ok
  asm volatile("" ::: "memory");
  #pragma unroll
  for (int i = 0; i < 4; i++)
  #pragma unroll
  for (int j = 0; j < 4; j++)
    acc[i][j] = MFMA32(af[i], bf[j], acc[i][j]);
}

// ---------- setup: fp32->fp16 weights + DCT matrices ----------
__global__ __launch_bounds__(256) void k_setup(
    const float* __restrict__ lin_w, const float* __restrict__ tok_w,
    const float* __restrict__ out_w, _Float16* __restrict__ lwh,
    _Float16* __restrict__ twh, _Float16* __restrict__ owh,
    _Float16* __restrict__ wmg, _Float16* __restrict__ wmtg) {
  int t = blockIdx.x * 256 + threadIdx.x;
  if (t < 768*384) lwh[t] = (_Float16)lin_w[t];
  if (t < 384*384) { twh[t] = (_Float16)tok_w[t]; owh[t] = (_Float16)out_w[t]; }
  if (t < 4096) {
    int n = t >> 6, h = t & 63;
    float v = cosf((float)n * ((float)h + 0.5f) * (PI_F / 64.0f)) * 0.1767766952966369f;
    if (n == 0) v *= 0.7071067811865476f;
    wmg[n*64 + h]  = (_Float16)v;
    wmtg[h*64 + n] = (_Float16)v;
  }
}

// ---------- merged: depthwise conv (blocks 0..767) + tok gate (768..1151) ----------
// Independent work items; memory-heavy conv co-schedules with MFMA/trig gate.
__global__ __launch_bounds__(256) void k_dwgate(
    const float* __restrict__ x, const float* __restrict__ dww,
    const float* __restrict__ dwb, _Float16* __restrict__ xdw,
    const float* __restrict__ fe, const _Float16* __restrict__ twh,
    const float* __restrict__ tkb, const float* __restrict__ cc,
    const float* __restrict__ aa, _Float16* __restrict__ g) {
  __shared__ __align__(16) char smem[37376];
  int t = threadIdx.x;
  if (blockIdx.x < 768) {
    // ---- dwconv body (h-strip of 4 rows) ----
    float* wsm = (float*)smem;                      // [576]
    float* bsm = (float*)(smem + 2304);             // [64]
    _Float16* buf = (_Float16*)(smem + 2560);       // [4][64*68]
    int blk = blockIdx.x;
    int hs = blk & 15;
    int rest = blk >> 4;
    int cgi = rest % 6;
    int b = rest / 6;
    int c0 = cgi * 64;
    int h0 = hs * 4;
    for (int i = t; i < 576; i += 256) wsm[i] = dww[c0*9 + i];
    if (t < 64) bsm[t] = dwb[c0 + t];
    __syncthreads();
    int lane = t & 63;
    int wslot = lane & 15, w4 = wslot * 4;
    int cs = t >> 4;
    bool wlo = (wslot == 0), whi = (wslot == 15);
    int lm = (lane - 1) & 63, lp = (lane + 1) & 63;
    const float* xb = x + (size_t)b * C_N * P_N + w4;
    f4 prev[4], cur[4];
    float pL[4], pR[4], cL[4], cR[4];
    #pragma unroll
    for (int q = 0; q < 4; q++) {
      const float* xc = xb + (size_t)(c0 + cs*4 + q) * P_N;
      prev[q] = (h0 > 0) ? *(const f4*)(xc + (h0-1)*64) : f4{0.f,0.f,0.f,0.f};
      cur[q]  = *(const f4*)(xc + h0*64);
      pL[q] = __shfl(prev[q][3], lm, 64); pR[q] = __shfl(prev[q][0], lp, 64);
      cL[q] = __shfl(cur[q][3],  lm, 64); cR[q] = __shfl(cur[q][0],  lp, 64);
      if (wlo) { pL[q] = 0.f; cL[q] = 0.f; }
      if (whi) { pR[q] = 0.f; cR[q] = 0.f; }
    }
    #pragma unroll
    for (int r = 0; r < 4; r++) {
      int h = h0 + r;
      float o[4][4];
      #pragma unroll
      for (int q = 0; q < 4; q++) {
        int lc = cs*4 + q;
        const float* xc = xb + (size_t)(c0 + lc) * P_N;
        f4 nxt = (h < 63) ? *(const f4*)(xc + (h+1)*64) : f4{0.f,0.f,0.f,0.f};
        float nL = __shfl(nxt[3], lm, 64), nR = __shfl(nxt[0], lp, 64);
        if (wlo) nL = 0.f;
        if (whi) nR = 0.f;
        float k0=wsm[lc*9+0],k1=wsm[lc*9+1],k2=wsm[lc*9+2];
        float k3=wsm[lc*9+3],k4=wsm[lc*9+4],k5=wsm[lc*9+5];
        float k6=wsm[lc*9+6],k7=wsm[lc*9+7],k8=wsm[lc*9+8];
        float bias = bsm[lc];
        #pragma unroll
        for (int e = 0; e < 4; e++) {
          float tl = (e > 0) ? prev[q][e-1] : pL[q];
          float tr = (e < 3) ? prev[q][e+1] : pR[q];
          float ml = (e > 0) ? cur[q][e-1]  : cL[q];
          float mr = (e < 3) ? cur[q][e+1]  : cR[q];
          float bl = (e > 0) ? nxt[e-1]     : nL;
          float br = (e < 3) ? nxt[e+1]     : nR;
          float acc = bias;
          acc += k0*tl + k1*prev[q][e] + k2*tr;
          acc += k3*ml + k4*cur[q][e]  + k5*mr;
          acc += k6*bl + k7*nxt[e]     + k8*br;
          o[q][e] = acc;
        }
        prev[q] = cur[q]; pL[q] = cL[q]; pR[q] = cR[q];
        cur[q] = nxt;     cL[q] = nL;    cR[q] = nR;
      }
      #pragma unroll
      for (int e = 0; e < 4; e++) {
        h4 hv;
        #pragma unroll
        for (int q = 0; q < 4; q++) hv[q] = (_Float16)o[q][e];
        *(h4*)&buf[r*4352 + (w4 + e) * 68 + cs * 4] = hv;
      }
    }
    __syncthreads();
    #pragma unroll
    for (int r = 0; r < 4; r++) {
      _Float16* op = xdw + ((size_t)b*P_N + (h0 + r)*64) * C_N + c0;
      #pragma unroll
      for (int i = 0; i < 4; i++) {
        int flat = (t + 256*i) * 4;
        int pix = flat >> 6, cl = flat & 63;
        *(h4*)&op[(size_t)pix*C_N + cl] = *(const h4*)&buf[r*4352 + pix*68 + cl];
      }
    }
  } else {
    // ---- gate body ----
    _Float16* la = (_Float16*)smem;                 // [64*40]
    _Float16* lb = (_Float16*)(smem + 5120);        // [64*40]
    int blk = blockIdx.x - 768;
    int pt = blk & 63, dt = blk >> 6;
    int p0 = pt*64, d0 = dt*64;
    int lane = t & 63, wave = t >> 6;
    int quad = lane >> 4, l15 = lane & 15;
    int wm_ = wave >> 1, wn = wave & 1;
    int srow = t >> 2, scg = (t & 3) * 8;
    f4 acc[2][2] = {};
    for (int kc = 0; kc < 384; kc += 32) {
      const float* src = fe + (size_t)(p0 + srow)*384 + kc + scg;
      f4 v0 = *(const f4*)src;
      f4 v1 = *(const f4*)(src + 4);
      h8 hv;
      hv[0]=(_Float16)v0[0]; hv[1]=(_Float16)v0[1]; hv[2]=(_Float16)v0[2]; hv[3]=(_Float16)v0[3];
      hv[4]=(_Float16)v1[0]; hv[5]=(_Float16)v1[1]; hv[6]=(_Float16)v1[2]; hv[7]=(_Float16)v1[3];
      *(h8*)&la[srow*40 + scg] = hv;
      *(h8*)&lb[srow*40 + scg] = *(const h8*)&twh[(size_t)(d0 + srow)*384 + kc + scg];
      __syncthreads();
      h8 a0 = *(const h8*)&la[(wm_*32 + l15)*40 + quad*8];
      h8 a1 = *(const h8*)&la[(wm_*32 + 16 + l15)*40 + quad*8];
      h8 b0 = *(const h8*)&lb[(wn*32 + l15)*40 + quad*8];
      h8 b1 = *(const h8*)&lb[(wn*32 + 16 + l15)*40 + quad*8];
      acc[0][0] = MFMA32(a0, b0, acc[0][0]);
      acc[0][1] = MFMA32(a0, b1, acc[0][1]);
      acc[1][0] = MFMA32(a1, b0, acc[1][0]);
      acc[1][1] = MFMA32(a1, b1, acc[1][1]);
      __syncthreads();
    }
    float c0 = cc[0];
    float s1 = (1.0f + 0.5f*aa[0]) / c0;
    #pragma unroll
    for (int i = 0; i < 2; i++)
    #pragma unroll
    for (int j = 0; j < 2; j++) {
      int d  = d0 + wn*32 + j*16 + l15;
      int pl = wm_*32 + i*16 + quad*4;
      float bias = tkb[d];
      h4 hv;
      #pragma unroll
      for (int r = 0; r < 4; r++) {
        float tv = fmaxf(acc[i][j][r] + bias, 0.0f);
        hv[r] = (_Float16)(__cosf(c0*tv) + s1*__sinf(c0*tv));
      }
      *(h4*)&g[(size_t)d*P_N + p0 + pl] = hv;
    }
  }
}

// ---------- GEMM1: 128x128, counted-vmcnt 2-phase + T2 swizzle (R4-best) ----------
__global__ __launch_bounds__(256) void k_gemm1(
    const _Float16* __restrict__ xdw, const _Float16* __restrict__ lwh,
    const float* __restrict__ lnb, _Float16* __restrict__ xs,
    _Float16* __restrict__ zs) {
  int pt = blockIdx.x & 31;
  int rest = blockIdx.x >> 5;
  int dt = rest % 6, b = rest / 6;
  int p0 = pt * 128, d0 = dt * 128;
  int t = threadIdx.x, lane = t & 63, wave = t >> 6;
  int quad = lane >> 4, l15 = lane & 15;
  int wm = wave >> 1, wn = wave & 1;
  __shared__ _Float16 la0[128 * 32], lb0[128 * 32];
  __shared__ _Float16 la1[128 * 32], lb1[128 * 32];
  int s_row = lane >> 2;
  int scol2 = (((lane & 3) ^ (s_row & 3)) * 8);   // T2 pre-swizzled source col
  const _Float16* ga = xdw + ((size_t)b*P_N + p0) * 384 + scol2;
  const _Float16* gb = lwh + (size_t)d0 * 384 + scol2;
  f4 acc[4][4] = {};
  #pragma unroll
  for (int s = 0; s < 2; s++) {
    int seg = wave * 2 + s;
    int row = seg * 16 + s_row;
    gl_lds16(ga + (size_t)row*384, &la0[seg*512 + lane*8]);
    gl_lds16(gb + (size_t)row*384, &lb0[seg*512 + lane*8]);
  }
  #pragma unroll
  for (int kt = 0; kt < 6; kt++) {
    int kc = kt * 64;
    gemm_step(ga, gb, kc + 32,  true,            la0, lb0, la1, lb1, acc);
    gemm_step(ga, gb, kc + 64,  (kc + 64 < 384), la1, lb1, la0, lb0, acc);
  }
  bool isz = (d0 >= 384);
  #pragma unroll
  for (int j = 0; j < 4; j++) {
    int d = d0 + wn*64 + j*16 + l15;
    float bias = lnb[d];
    _Float16* dst = isz ? (zs + ((size_t)b*C_N + (d-384)) * P_N)
                        : (xs + ((size_t)b*C_N + d) * P_N);
    #pragma unroll
    for (int i = 0; i < 4; i++) {
      int p = p0 + wm*64 + i*16 + quad*4;
      h4 hv;
      if (isz) {
        #pragma unroll
        for (int r = 0; r < 4; r++) {
          float v = acc[i][j][r] + bias;
          v = v / (1.0f + __expf(-v));
          hv[r] = (_Float16)v;
        }
      } else {
        #pragma unroll
        for (int r = 0; r < 4; r++) hv[r] = (_Float16)(acc[i][j][r] + bias);
      }
      *(h4*)&dst[p] = hv;
    }
  }
}

// ---------- fused DCT -> gate -> IDCT ----------
__global__ __launch_bounds__(256) void k_dct(
    const _Float16* __restrict__ xs, const _Float16* __restrict__ g,
    const _Float16* __restrict__ wmg, const _Float16* __restrict__ wmtg,
    _Float16* __restrict__ xi) {
  int b = blockIdx.x / 96, cg = blockIdx.x % 96;
  int c0 = cg * 4;
  int t = threadIdx.x, wave = t >> 6, lane = t & 63;
  int quad = lane >> 4, l15 = lane & 15;
  __shared__ _Float16 wm_s[64*72];
  __shared__ _Float16 wmt_s[64*72];
  __shared__ _Float16 pb[4][64*72];
  for (int i = t; i < 512; i += 256) {
    int row = i >> 3, col = (i & 7) * 8;
    *(h8*)&wm_s[row*72 + col]  = *(const h8*)&wmg[row*64 + col];
    *(h8*)&wmt_s[row*72 + col] = *(const h8*)&wmtg[row*64 + col];
  }
  const _Float16* xsb = xs + ((size_t)b*C_N + c0) * P_N;
  for (int i = t; i < 2048; i += 256) {
    int pl = i >> 9, idx = i & 511;
    int p = idx * 8, hh = p >> 6, ww = p & 63;
    *(h8*)&pb[pl][hh*72 + ww] = *(const h8*)&xsb[(size_t)pl*P_N + p];
  }
  __syncthreads();
  h8 aS[4][2], bW[4][2];
  #pragma unroll
  for (int I = 0; I < 4; I++)
  #pragma unroll
  for (int kk = 0; kk < 2; kk++) {
    aS[I][kk] = *(const h8*)&pb[wave][(I*16 + l15)*72 + kk*32 + quad*8];
    bW[I][kk] = *(const h8*)&wm_s[(I*16 + l15)*72 + kk*32 + quad*8];
  }
  h4 t1h[4][4];
  #pragma unroll
  for (int I = 0; I < 4; I++)
  #pragma unroll
  for (int J = 0; J < 4; J++) {
    f4 a = {};
    a = MFMA32(aS[I][0], bW[J][0], a);
    a = MFMA32(aS[I][1], bW[J][1], a);
    t1h[I][J] = to_h4(a);
  }
  __syncthreads();
  // stage gate TRANSPOSED: pb[pl][k*72 + n] via 4x8 register transpose
  const _Float16* gb = g + (size_t)c0 * P_N;
  #pragma unroll
  for (int i = 0; i < 2; i++) {
    int id = t + 256 * i;            // 512 tasks: 4 planes x 16 n-quads x 8 k-groups
    int pl = id >> 7;
    int r7 = id & 127;
    int n4 = (r7 >> 3) * 4;
    int k8 = (r7 & 7) * 8;
    h8 v[4];
    #pragma unroll
    for (int q = 0; q < 4; q++)
      v[q] = *(const h8*)&gb[(size_t)pl*P_N + (n4 + q)*64 + k8];
    #pragma unroll
    for (int e = 0; e < 8; e++) {
      h4 w;
      #pragma unroll
      for (int q = 0; q < 4; q++) w[q] = v[q][e];
      *(h4*)&pb[pl][(k8 + e)*72 + n4] = w;
    }
  }
  __syncthreads();
  f4 t2[4][4] = {};
  #pragma unroll
  for (int I = 0; I < 4; I++)
  #pragma unroll
  for (int K4 = 0; K4 < 4; K4++) {
    h4 af = *(const h4*)&wm_s[(I*16 + l15)*72 + K4*16 + quad*4];
    #pragma unroll
    for (int J = 0; J < 4; J++) t2[I][J] = MFMA16(af, t1h[K4][J], t2[I][J]);
  }
  h4 fh[4][4];
  #pragma unroll
  for (int I = 0; I < 4; I++)
  #pragma unroll
  for (int J = 0; J < 4; J++) {
    h4 gv4 = *(const h4*)&pb[wave][(J*16 + l15)*72 + I*16 + quad*4];
    h4 r;
    #pragma unroll
    for (int rr = 0; rr < 4; rr++)
      r[rr] = (_Float16)(t2[I][J][rr] * (float)gv4[rr]);
    fh[I][J] = r;
  }
  f4 t3[4][4] = {};
  #pragma unroll
  for (int J = 0; J < 4; J++)
  #pragma unroll
  for (int K4 = 0; K4 < 4; K4++) {
    h4 bf = *(const h4*)&wmt_s[(J*16 + l15)*72 + K4*16 + quad*4];
    #pragma unroll
    for (int I = 0; I < 4; I++) t3[I][J] = MFMA16(fh[K4][I], bf, t3[I][J]);
  }
  h4 t3h[4][4];
  #pragma unroll
  for (int I = 0; I < 4; I++)
  #pragma unroll
  for (int J = 0; J < 4; J++) t3h[I][J] = to_h4(t3[I][J]);
  f4 t4[4][4] = {};
  #pragma unroll
  for (int I = 0; I < 4; I++)
  #pragma unroll
  for (int K4 = 0; K4 < 4; K4++) {
    h4 af = *(const h4*)&wmt_s[(I*16 + l15)*72 + K4*16 + quad*4];
    #pragma unroll
    for (int J = 0; J < 4; J++) t4[I][J] = MFMA16(af, t3h[K4][J], t4[I][J]);
  }
  #pragma unroll
  for (int I = 0; I < 4; I++)
  #pragma unroll
  for (int J = 0; J < 4; J++) {
    int w0 = I*16 + quad*4, hq = J*16 + l15;
    *(h4*)&pb[wave][hq*72 + w0] = to_h4(t4[I][J]);
  }
  __syncthreads();
  _Float16* xib = xi + ((size_t)b*C_N + c0) * P_N;
  for (int i = t; i < 2048; i += 256) {
    int pl = i >> 9, idx = i & 511;
    int p = idx * 8, hh = p >> 6, ww = p & 63;
    *(h8*)&xib[(size_t)pl*P_N + p] = *(const h8*)&pb[pl][hh*72 + ww];
  }
}

// ---------- fused LN+silu+GEMM2: 64-px tile, 8 waves (48 d-cols each) ----------
__global__ __launch_bounds__(512) void k_fuse(
    const _Float16* __restrict__ xi, const _Float16* __restrict__ zs,
    const float* __restrict__ lng, const float* __restrict__ lnbv,
    const _Float16* __restrict__ owh, const float* __restrict__ ob,
    float* __restrict__ out) {
  int b = blockIdx.x >> 6, pt = blockIdx.x & 63;
  int p0 = pt * 64;
  int t = threadIdx.x;
  __shared__ _Float16 ut[64 * 392];
  __shared__ float red[8][64], red2[8][64];
  __shared__ float muL[64], rsL[64];
  const _Float16* xib = xi + (size_t)b * C_N * P_N;
  #pragma unroll
  for (int i = 0; i < 2; i++) {
    int id = t + 512 * i;
    if (id < 768) {
      int px0 = (id & 7) * 8;
      int c4 = (id >> 3) * 4;
      h8 v[4];
      #pragma unroll
      for (int q = 0; q < 4; q++)
        v[q] = *(const h8*)&xib[(size_t)(c4 + q) * P_N + p0 + px0];
      #pragma unroll
      for (int e = 0; e < 8; e++) {
        h4 w;
        #pragma unroll
        for (int q = 0; q < 4; q++) w[q] = v[q][e];
        *(h4*)&ut[(px0 + e) * 392 + c4] = w;
      }
    }
  }
  __syncthreads();
  int px = t & 63, seg = t >> 6;
  float s = 0.f, ss = 0.f;
  #pragma unroll
  for (int j = 0; j < 6; j++) {
    h8 v = *(const h8*)&ut[px * 392 + seg * 48 + j * 8];
    #pragma unroll
    for (int e = 0; e < 8; e++) { float f = (float)v[e]; s += f; ss += f * f; }
  }
  red[seg][px] = s; red2[seg][px] = ss;
  __syncthreads();
  if (t < 64) {
    float st = 0.f, sst = 0.f;
    #pragma unroll
    for (int sg = 0; sg < 8; sg++) { st += red[sg][t]; sst += red2[sg][t]; }
    float m = st * (1.f/384.f);
    float var = sst * (1.f/384.f) - m * m;
    muL[t] = m; rsL[t] = rsqrtf(var + 1e-5f);
  }
  __syncthreads();
  const _Float16* zb = zs + (size_t)b * C_N * P_N;
  #pragma unroll
  for (int i = 0; i < 2; i++) {
    int id = t + 512 * i;
    if (id < 768) {
      int px0 = (id & 7) * 8;
      int c4 = (id >> 3) * 4;
      f4 g4 = *(const f4*)&lng[c4];
      f4 b4 = *(const f4*)&lnbv[c4];
      h8 z[4];
      #pragma unroll
      for (int q = 0; q < 4; q++)
        z[q] = *(const h8*)&zb[(size_t)(c4 + q) * P_N + p0 + px0];
      #pragma unroll
      for (int e = 0; e < 8; e++) {
        int p = px0 + e;
        h4 y = *(const h4*)&ut[p * 392 + c4];
        float mu = muL[p], rs = rsL[p];
        #pragma unroll
        for (int q = 0; q < 4; q++) {
          float f = ((float)y[q] - mu) * rs * g4[q] + b4[q];
          y[q] = (_Float16)(f * (float)z[q][e]);
        }
        *(h4*)&ut[p * 392 + c4] = y;
      }
    }
  }
  __syncthreads();
  int lane = t & 63, wave = t >> 6;
  int quad = lane >> 4, l15 = lane & 15;
  int n0 = wave * 48;
  f4 acc[4][3] = {};
  const _Float16* bw = owh + (size_t)(n0 + l15) * 384 + quad * 8;
  #pragma unroll
  for (int kc = 0; kc < 384; kc += 32) {
    h8 af[4], bf[3];
    #pragma unroll
    for (int i = 0; i < 4; i++)
      af[i] = *(const h8*)&ut[(i*16 + l15) * 392 + kc + quad*8];
    #pragma unroll
    for (int j = 0; j < 3; j++)
      bf[j] = *(const h8*)&bw[(size_t)(j*16) * 384 + kc];
    #pragma unroll
    for (int i = 0; i < 4; i++)
    #pragma unroll
    for (int j = 0; j < 3; j++)
      acc[i][j] = MFMA32(af[i], bf[j], acc[i][j]);
  }
  #pragma unroll
  for (int j = 0; j < 3; j++) {
    int d = n0 + j*16 + l15;
    float bias = ob[d];
    float* op = out + ((size_t)b*C_N + d) * P_N + p0;
    #pragma unroll
    for (int i = 0; i < 4; i++) {
      f4 v;
      #pragma unroll
      for (int r = 0; r < 4; r++) v[r] = acc[i][j][r] + bias;
      *(f4*)&op[i*16 + quad*4] = v;
    }
  }
}

extern "C" void kernel_launch(void* const* d_in, const int* in_sizes, int n_in,
                              void* d_out, int out_size, void* d_ws, size_t ws_size,
                              hipStream_t stream) {
  (void)in_sizes; (void)n_in; (void)out_size; (void)ws_size;
  const float* x    = (const float*)d_in[0];
  const float* fe   = (const float*)d_in[1];
  const float* dww  = (const float*)d_in[2];
  const float* dwb  = (const float*)d_in[3];
  const float* linw = (const float*)d_in[4];
  const float* linb = (const float*)d_in[5];
  const float* tokw = (const float*)d_in[6];
  const float* tokb = (const float*)d_in[7];
  const float* cc   = (const float*)d_in[8];
  const float* aa   = (const float*)d_in[9];
  const float* lng  = (const float*)d_in[10];
  const float* lnbv = (const float*)d_in[11];
  const float* outw = (const float*)d_in[12];
  const float* outb = (const float*)d_in[13];
  float* out = (float*)d_out;

  char* ws = (char*)d_ws;
  size_t off = 0;
  auto alloc = [&](size_t bytes) -> void* {
    void* p = ws + off;
    off += (bytes + 255) & ~(size_t)255;
    return p;
  };
  _Float16* lwh  = (_Float16*)alloc((size_t)768*384*2);
  _Float16* twh  = (_Float16*)alloc((size_t)384*384*2);
  _Float16* owh  = (_Float16*)alloc((size_t)384*384*2);
  _Float16* wmg  = (_Float16*)alloc((size_t)64*64*2);
  _Float16* wmtg = (_Float16*)alloc((size_t)64*64*2);
  _Float16* xdw  = (_Float16*)alloc((size_t)B_N*P_N*C_N*2);
  _Float16* xs   = (_Float16*)alloc((size_t)B_N*C_N*P_N*2);
  _Float16* zs   = (_Float16*)alloc((size_t)B_N*C_N*P_N*2);
  _Float16* gg   = (_Float16*)alloc((size_t)C_N*P_N*2);
  _Float16* xi   = xdw;   // xdw dead after k_gemm1

  k_setup<<<1152, 256, 0, stream>>>(linw, tokw, outw, lwh, twh, owh, wmg, wmtg);
  k_dwgate<<<1152, 256, 0, stream>>>(x, dww, dwb, xdw, fe, twh, tokb, cc, aa, gg);
  k_gemm1<<<1536, 256, 0, stream>>>(xdw, lwh, linb, xs, zs);
  k_dct<<<768, 256, 0, stream>>>(xs, gg, wmg, wmtg, xi);
  k_fuse<<<512, 512, 0, stream>>>(xi, zs, lng, lnbv, owh, outb, out);
}

// Round 16
// 223.863 us; speedup vs baseline: 1.1141x; 1.0221x over previous
//
#include <hip/hip_runtime.h>

typedef _Float16 h2 __attribute__((ext_vector_type(2)));
typedef _Float16 h4 __attribute__((ext_vector_type(4)));
typedef _Float16 h8 __attribute__((ext_vector_type(8)));
typedef float    f4 __attribute__((ext_vector_type(4)));

#define MFMA32(a,b,c) __builtin_amdgcn_mfma_f32_16x16x32_f16((a),(b),(c),0,0,0)
#define MFMA16(a,b,c) __builtin_amdgcn_mfma_f32_16x16x16f16((a),(b),(c),0,0,0)

#define B_N 8
#define C_N 384
#define P_N 4096
#define PI_F 3.14159265358979323846f

__device__ __forceinline__ h4 to_h4(f4 v) {
  h4 r; r[0]=(_Float16)v[0]; r[1]=(_Float16)v[1]; r[2]=(_Float16)v[2]; r[3]=(_Float16)v[3];
  return r;
}

// async global->LDS, 16B per lane; LDS dest = wave-uniform base + lane*16 (m97/m104)
__device__ __forceinline__ void gl_lds16(const _Float16* g, _Float16* l) {
  __builtin_amdgcn_global_load_lds(
      (const __attribute__((address_space(1))) void*)g,
      (__attribute__((address_space(3))) void*)l, 16, 0, 0);
}

// one K-step: counted vmcnt + raw barriers (T3/T4 minimum form), T2 chunk-XOR
// swizzle (pre-swizzled global src, swizzled ds_read; LDS dest linear).
__device__ __forceinline__ void gemm_step(
    const _Float16* __restrict__ ga, const _Float16* __restrict__ gb,
    int kcn, bool pref,
    _Float16* laC, _Float16* lbC, _Float16* laN, _Float16* lbN,
    f4 (&acc)[4][4]) {
  int t = threadIdx.x, lane = t & 63, wave = t >> 6;
  int quad = lane >> 4, l15 = lane & 15;
  int wm = wave >> 1, wn = wave & 1;
  int s_row = lane >> 2;
  if (pref) {
    #pragma unroll
    for (int s = 0; s < 2; s++) {
      int seg = wave * 2 + s;
      int row = seg * 16 + s_row;
      gl_lds16(ga + (size_t)row*384 + kcn, &laN[seg*512 + lane*8]);
      gl_lds16(gb + (size_t)row*384 + kcn, &lbN[seg*512 + lane*8]);
    }
    // wait own PREVIOUS step's 4 staging loads (oldest); 4 new stay in flight
    asm volatile("s_waitcnt vmcnt(4)" ::: "memory");
  } else {
    asm volatile("s_waitcnt vmcnt(0)" ::: "memory");
  }
  __builtin_amdgcn_s_barrier();          // all waves: current buffers staged
  asm volatile("" ::: "memory");
  h8 af[4], bf[4];
  int sq = (quad ^ (l15 & 3)) * 8;       // read-side swizzle (row&3 == l15&3)
  #pragma unroll
  for (int i = 0; i < 4; i++) {
    af[i] = *(const h8*)&laC[(wm*64 + i*16 + l15)*32 + sq];
    bf[i] = *(const h8*)&lbC[(wn*64 + i*16 + l15)*32 + sq];
  }
  asm volatile("s_waitcnt lgkmcnt(0)" ::: "memory");
  __builtin_amdgcn_s_barrier();          // all waves: reads done -> overwrite ok
  asm volatile("" ::: "memory");
  #pragma unroll
  for (int i = 0; i < 4; i++)
  #pragma unroll
  for (int j = 0; j < 4; j++)
    acc[i][j] = MFMA32(af[i], bf[j], acc[i][j]);
}

// ---------- setup: fp32->fp16 weights + DCT matrices ----------
__global__ __launch_bounds__(256) void k_setup(
    const float* __restrict__ lin_w, const float* __restrict__ tok_w,
    const float* __restrict__ out_w, _Float16* __restrict__ lwh,
    _Float16* __restrict__ twh, _Float16* __restrict__ owh,
    _Float16* __restrict__ wmg, _Float16* __restrict__ wmtg) {
  int t = blockIdx.x * 256 + threadIdx.x;
  if (t < 768*384) lwh[t] = (_Float16)lin_w[t];
  if (t < 384*384) { twh[t] = (_Float16)tok_w[t]; owh[t] = (_Float16)out_w[t]; }
  if (t < 4096) {
    int n = t >> 6, h = t & 63;
    float v = cosf((float)n * ((float)h + 0.5f) * (PI_F / 64.0f)) * 0.1767766952966369f;
    if (n == 0) v *= 0.7071067811865476f;
    wmg[n*64 + h]  = (_Float16)v;
    wmtg[h*64 + n] = (_Float16)v;
  }
}

// ---------- merged: depthwise conv (blocks 0..767) + tok gate (768..1151) ----------
__global__ __launch_bounds__(256) void k_dwgate(
    const float* __restrict__ x, const float* __restrict__ dww,
    const float* __restrict__ dwb, _Float16* __restrict__ xdw,
    const float* __restrict__ fe, const _Float16* __restrict__ twh,
    const float* __restrict__ tkb, const float* __restrict__ cc,
    const float* __restrict__ aa, _Float16* __restrict__ g) {
  __shared__ __align__(16) char smem[37376];
  int t = threadIdx.x;
  if (blockIdx.x < 768) {
    // ---- dwconv body (h-strip of 4 rows) ----
    float* wsm = (float*)smem;                      // [576]
    float* bsm = (float*)(smem + 2304);             // [64]
    _Float16* buf = (_Float16*)(smem + 2560);       // [4][64*68]
    int blk = blockIdx.x;
    int hs = blk & 15;
    int rest = blk >> 4;
    int cgi = rest % 6;
    int b = rest / 6;
    int c0 = cgi * 64;
    int h0 = hs * 4;
    for (int i = t; i < 576; i += 256) wsm[i] = dww[c0*9 + i];
    if (t < 64) bsm[t] = dwb[c0 + t];
    __syncthreads();
    int lane = t & 63;
    int wslot = lane & 15, w4 = wslot * 4;
    int cs = t >> 4;
    bool wlo = (wslot == 0), whi = (wslot == 15);
    int lm = (lane - 1) & 63, lp = (lane + 1) & 63;
    const float* xb = x + (size_t)b * C_N * P_N + w4;
    f4 prev[4], cur[4];
    float pL[4], pR[4], cL[4], cR[4];
    #pragma unroll
    for (int q = 0; q < 4; q++) {
      const float* xc = xb + (size_t)(c0 + cs*4 + q) * P_N;
      prev[q] = (h0 > 0) ? *(const f4*)(xc + (h0-1)*64) : f4{0.f,0.f,0.f,0.f};
      cur[q]  = *(const f4*)(xc + h0*64);
      pL[q] = __shfl(prev[q][3], lm, 64); pR[q] = __shfl(prev[q][0], lp, 64);
      cL[q] = __shfl(cur[q][3],  lm, 64); cR[q] = __shfl(cur[q][0],  lp, 64);
      if (wlo) { pL[q] = 0.f; cL[q] = 0.f; }
      if (whi) { pR[q] = 0.f; cR[q] = 0.f; }
    }
    #pragma unroll
    for (int r = 0; r < 4; r++) {
      int h = h0 + r;
      float o[4][4];
      #pragma unroll
      for (int q = 0; q < 4; q++) {
        int lc = cs*4 + q;
        const float* xc = xb + (size_t)(c0 + lc) * P_N;
        f4 nxt = (h < 63) ? *(const f4*)(xc + (h+1)*64) : f4{0.f,0.f,0.f,0.f};
        float nL = __shfl(nxt[3], lm, 64), nR = __shfl(nxt[0], lp, 64);
        if (wlo) nL = 0.f;
        if (whi) nR = 0.f;
        float k0=wsm[lc*9+0],k1=wsm[lc*9+1],k2=wsm[lc*9+2];
        float k3=wsm[lc*9+3],k4=wsm[lc*9+4],k5=wsm[lc*9+5];
        float k6=wsm[lc*9+6],k7=wsm[lc*9+7],k8=wsm[lc*9+8];
        float bias = bsm[lc];
        #pragma unroll
        for (int e = 0; e < 4; e++) {
          float tl = (e > 0) ? prev[q][e-1] : pL[q];
          float tr = (e < 3) ? prev[q][e+1] : pR[q];
          float ml = (e > 0) ? cur[q][e-1]  : cL[q];
          float mr = (e < 3) ? cur[q][e+1]  : cR[q];
          float bl = (e > 0) ? nxt[e-1]     : nL;
          float br = (e < 3) ? nxt[e+1]     : nR;
          float acc = bias;
          acc += k0*tl + k1*prev[q][e] + k2*tr;
          acc += k3*ml + k4*cur[q][e]  + k5*mr;
          acc += k6*bl + k7*nxt[e]     + k8*br;
          o[q][e] = acc;
        }
        prev[q] = cur[q]; pL[q] = cL[q]; pR[q] = cR[q];
        cur[q] = nxt;     cL[q] = nL;    cR[q] = nR;
      }
      #pragma unroll
      for (int e = 0; e < 4; e++) {
        h4 hv;
        #pragma unroll
        for (int q = 0; q < 4; q++) hv[q] = (_Float16)o[q][e];
        *(h4*)&buf[r*4352 + (w4 + e) * 68 + cs * 4] = hv;
      }
    }
    __syncthreads();
    #pragma unroll
    for (int r = 0; r < 4; r++) {
      _Float16* op = xdw + ((size_t)b*P_N + (h0 + r)*64) * C_N + c0;
      #pragma unroll
      for (int i = 0; i < 4; i++) {
        int flat = (t + 256*i) * 4;
        int pix = flat >> 6, cl = flat & 63;
        *(h4*)&op[(size_t)pix*C_N + cl] = *(const h4*)&buf[r*4352 + pix*68 + cl];
      }
    }
  } else {
    // ---- gate body ----
    _Float16* la = (_Float16*)smem;                 // [64*40]
    _Float16* lb = (_Float16*)(smem + 5120);        // [64*40]
    int blk = blockIdx.x - 768;
    int pt = blk & 63, dt = blk >> 6;
    int p0 = pt*64, d0 = dt*64;
    int lane = t & 63, wave = t >> 6;
    int quad = lane >> 4, l15 = lane & 15;
    int wm_ = wave >> 1, wn = wave & 1;
    int srow = t >> 2, scg = (t & 3) * 8;
    f4 acc[2][2] = {};
    for (int kc = 0; kc < 384; kc += 32) {
      const float* src = fe + (size_t)(p0 + srow)*384 + kc + scg;
      f4 v0 = *(const f4*)src;
      f4 v1 = *(const f4*)(src + 4);
      h8 hv;
      hv[0]=(_Float16)v0[0]; hv[1]=(_Float16)v0[1]; hv[2]=(_Float16)v0[2]; hv[3]=(_Float16)v0[3];
      hv[4]=(_Float16)v1[0]; hv[5]=(_Float16)v1[1]; hv[6]=(_Float16)v1[2]; hv[7]=(_Float16)v1[3];
      *(h8*)&la[srow*40 + scg] = hv;
      *(h8*)&lb[srow*40 + scg] = *(const h8*)&twh[(size_t)(d0 + srow)*384 + kc + scg];
      __syncthreads();
      h8 a0 = *(const h8*)&la[(wm_*32 + l15)*40 + quad*8];
      h8 a1 = *(const h8*)&la[(wm_*32 + 16 + l15)*40 + quad*8];
      h8 b0 = *(const h8*)&lb[(wn*32 + l15)*40 + quad*8];
      h8 b1 = *(const h8*)&lb[(wn*32 + 16 + l15)*40 + quad*8];
      acc[0][0] = MFMA32(a0, b0, acc[0][0]);
      acc[0][1] = MFMA32(a0, b1, acc[0][1]);
      acc[1][0] = MFMA32(a1, b0, acc[1][0]);
      acc[1][1] = MFMA32(a1, b1, acc[1][1]);
      __syncthreads();
    }
    float c0 = cc[0];
    float s1 = (1.0f + 0.5f*aa[0]) / c0;
    #pragma unroll
    for (int i = 0; i < 2; i++)
    #pragma unroll
    for (int j = 0; j < 2; j++) {
      int d  = d0 + wn*32 + j*16 + l15;
      int pl = wm_*32 + i*16 + quad*4;
      float bias = tkb[d];
      h4 hv;
      #pragma unroll
      for (int r = 0; r < 4; r++) {
        float tv = fmaxf(acc[i][j][r] + bias, 0.0f);
        hv[r] = (_Float16)(__cosf(c0*tv) + s1*__sinf(c0*tv));
      }
      *(h4*)&g[(size_t)d*P_N + p0 + pl] = hv;
    }
  }
}

// ---------- GEMM1: 128x128, counted-vmcnt 2-phase + T2 swizzle (R4-best) ----------
__global__ __launch_bounds__(256) void k_gemm1(
    const _Float16* __restrict__ xdw, const _Float16* __restrict__ lwh,
    const float* __restrict__ lnb, _Float16* __restrict__ xs,
    _Float16* __restrict__ zs) {
  int pt = blockIdx.x & 31;
  int rest = blockIdx.x >> 5;
  int dt = rest % 6, b = rest / 6;
  int p0 = pt * 128, d0 = dt * 128;
  int t = threadIdx.x, lane = t & 63, wave = t >> 6;
  int quad = lane >> 4, l15 = lane & 15;
  int wm = wave >> 1, wn = wave & 1;
  __shared__ _Float16 la0[128 * 32], lb0[128 * 32];
  __shared__ _Float16 la1[128 * 32], lb1[128 * 32];
  int s_row = lane >> 2;
  int scol2 = (((lane & 3) ^ (s_row & 3)) * 8);   // T2 pre-swizzled source col
  const _Float16* ga = xdw + ((size_t)b*P_N + p0) * 384 + scol2;
  const _Float16* gb = lwh + (size_t)d0 * 384 + scol2;
  f4 acc[4][4] = {};
  #pragma unroll
  for (int s = 0; s < 2; s++) {
    int seg = wave * 2 + s;
    int row = seg * 16 + s_row;
    gl_lds16(ga + (size_t)row*384, &la0[seg*512 + lane*8]);
    gl_lds16(gb + (size_t)row*384, &lb0[seg*512 + lane*8]);
  }
  #pragma unroll
  for (int kt = 0; kt < 6; kt++) {
    int kc = kt * 64;
    gemm_step(ga, gb, kc + 32,  true,            la0, lb0, la1, lb1, acc);
    gemm_step(ga, gb, kc + 64,  (kc + 64 < 384), la1, lb1, la0, lb0, acc);
  }
  bool isz = (d0 >= 384);
  #pragma unroll
  for (int j = 0; j < 4; j++) {
    int d = d0 + wn*64 + j*16 + l15;
    float bias = lnb[d];
    _Float16* dst = isz ? (zs + ((size_t)b*C_N + (d-384)) * P_N)
                        : (xs + ((size_t)b*C_N + d) * P_N);
    #pragma unroll
    for (int i = 0; i < 4; i++) {
      int p = p0 + wm*64 + i*16 + quad*4;
      h4 hv;
      if (isz) {
        #pragma unroll
        for (int r = 0; r < 4; r++) {
          float v = acc[i][j][r] + bias;
          v = v / (1.0f + __expf(-v));
          hv[r] = (_Float16)v;
        }
      } else {
        #pragma unroll
        for (int r = 0; r < 4; r++) hv[r] = (_Float16)(acc[i][j][r] + bias);
      }
      *(h4*)&dst[p] = hv;
    }
  }
}

// ---------- fused DCT -> gate -> IDCT (stride 68: 53KB LDS, 3 blocks/CU) ----------
__global__ __launch_bounds__(256) void k_dct(
    const _Float16* __restrict__ xs, const _Float16* __restrict__ g,
    const _Float16* __restrict__ wmg, const _Float16* __restrict__ wmtg,
    _Float16* __restrict__ xi) {
  int b = blockIdx.x / 96, cg = blockIdx.x % 96;
  int c0 = cg * 4;
  int t = threadIdx.x, wave = t >> 6, lane = t & 63;
  int quad = lane >> 4, l15 = lane & 15;
  __shared__ _Float16 wm_s[64*68];
  __shared__ _Float16 wmt_s[64*68];
  __shared__ _Float16 pb[4][64*68];
  for (int i = t; i < 512; i += 256) {
    int row = i >> 3, col = (i & 7) * 8;
    *(h8*)&wm_s[row*68 + col]  = *(const h8*)&wmg[row*64 + col];
    *(h8*)&wmt_s[row*68 + col] = *(const h8*)&wmtg[row*64 + col];
  }
  const _Float16* xsb = xs + ((size_t)b*C_N + c0) * P_N;
  for (int i = t; i < 2048; i += 256) {
    int pl = i >> 9, idx = i & 511;
    int p = idx * 8, hh = p >> 6, ww = p & 63;
    *(h8*)&pb[pl][hh*68 + ww] = *(const h8*)&xsb[(size_t)pl*P_N + p];
  }
  __syncthreads();
  h8 aS[4][2], bW[4][2];
  #pragma unroll
  for (int I = 0; I < 4; I++)
  #pragma unroll
  for (int kk = 0; kk < 2; kk++) {
    aS[I][kk] = *(const h8*)&pb[wave][(I*16 + l15)*68 + kk*32 + quad*8];
    bW[I][kk] = *(const h8*)&wm_s[(I*16 + l15)*68 + kk*32 + quad*8];
  }
  h4 t1h[4][4];
  #pragma unroll
  for (int I = 0; I < 4; I++)
  #pragma unroll
  for (int J = 0; J < 4; J++) {
    f4 a = {};
    a = MFMA32(aS[I][0], bW[J][0], a);
    a = MFMA32(aS[I][1], bW[J][1], a);
    t1h[I][J] = to_h4(a);
  }
  __syncthreads();
  // stage gate TRANSPOSED: pb[pl][k*68 + n] via 4x8 register transpose
  const _Float16* gb = g + (size_t)c0 * P_N;
  #pragma unroll
  for (int i = 0; i < 2; i++) {
    int id = t + 256 * i;            // 512 tasks: 4 planes x 16 n-quads x 8 k-groups
    int pl = id >> 7;
    int r7 = id & 127;
    int n4 = (r7 >> 3) * 4;
    int k8 = (r7 & 7) * 8;
    h8 v[4];
    #pragma unroll
    for (int q = 0; q < 4; q++)
      v[q] = *(const h8*)&gb[(size_t)pl*P_N + (n4 + q)*64 + k8];
    #pragma unroll
    for (int e = 0; e < 8; e++) {
      h4 w;
      #pragma unroll
      for (int q = 0; q < 4; q++) w[q] = v[q][e];
      *(h4*)&pb[pl][(k8 + e)*68 + n4] = w;
    }
  }
  __syncthreads();
  f4 t2[4][4] = {};
  #pragma unroll
  for (int I = 0; I < 4; I++)
  #pragma unroll
  for (int K4 = 0; K4 < 4; K4++) {
    h4 af = *(const h4*)&wm_s[(I*16 + l15)*68 + K4*16 + quad*4];
    #pragma unroll
    for (int J = 0; J < 4; J++) t2[I][J] = MFMA16(af, t1h[K4][J], t2[I][J]);
  }
  h4 fh[4][4];
  #pragma unroll
  for (int I = 0; I < 4; I++)
  #pragma unroll
  for (int J = 0; J < 4; J++) {
    h4 gv4 = *(const h4*)&pb[wave][(J*16 + l15)*68 + I*16 + quad*4];
    h4 r;
    #pragma unroll
    for (int rr = 0; rr < 4; rr++)
      r[rr] = (_Float16)(t2[I][J][rr] * (float)gv4[rr]);
    fh[I][J] = r;
  }
  f4 t3[4][4] = {};
  #pragma unroll
  for (int J = 0; J < 4; J++)
  #pragma unroll
  for (int K4 = 0; K4 < 4; K4++) {
    h4 bf = *(const h4*)&wmt_s[(J*16 + l15)*68 + K4*16 + quad*4];
    #pragma unroll
    for (int I = 0; I < 4; I++) t3[I][J] = MFMA16(fh[K4][I], bf, t3[I][J]);
  }
  h4 t3h[4][4];
  #pragma unroll
  for (int I = 0; I < 4; I++)
  #pragma unroll
  for (int J = 0; J < 4; J++) t3h[I][J] = to_h4(t3[I][J]);
  f4 t4[4][4] = {};
  #pragma unroll
  for (int I = 0; I < 4; I++)
  #pragma unroll
  for (int K4 = 0; K4 < 4; K4++) {
    h4 af = *(const h4*)&wmt_s[(I*16 + l15)*68 + K4*16 + quad*4];
    #pragma unroll
    for (int J = 0; J < 4; J++) t4[I][J] = MFMA16(af, t3h[K4][J], t4[I][J]);
  }
  #pragma unroll
  for (int I = 0; I < 4; I++)
  #pragma unroll
  for (int J = 0; J < 4; J++) {
    int w0 = I*16 + quad*4, hq = J*16 + l15;
    *(h4*)&pb[wave][hq*68 + w0] = to_h4(t4[I][J]);
  }
  __syncthreads();
  _Float16* xib = xi + ((size_t)b*C_N + c0) * P_N;
  for (int i = t; i < 2048; i += 256) {
    int pl = i >> 9, idx = i & 511;
    int p = idx * 8, hh = p >> 6, ww = p & 63;
    *(h8*)&xib[(size_t)pl*P_N + p] = *(const h8*)&pb[pl][hh*68 + ww];
  }
}

// ---------- fused LN+silu+GEMM2: 64-px tile, 8 waves (48 d-cols each) ----------
__global__ __launch_bounds__(512) void k_fuse(
    const _Float16* __restrict__ xi, const _Float16* __restrict__ zs,
    const float* __restrict__ lng, const float* __restrict__ lnbv,
    const _Float16* __restrict__ owh, const float* __restrict__ ob,
    float* __restrict__ out) {
  int b = blockIdx.x >> 6, pt = blockIdx.x & 63;
  int p0 = pt * 64;
  int t = threadIdx.x;
  __shared__ _Float16 ut[64 * 392];
  __shared__ float red[8][64], red2[8][64];
  __shared__ float muL[64], rsL[64];
  const _Float16* xib = xi + (size_t)b * C_N * P_N;
  #pragma unroll
  for (int i = 0; i < 2; i++) {
    int id = t + 512 * i;
    if (id < 768) {
      int px0 = (id & 7) * 8;
      int c4 = (id >> 3) * 4;
      h8 v[4];
      #pragma unroll
      for (int q = 0; q < 4; q++)
        v[q] = *(const h8*)&xib[(size_t)(c4 + q) * P_N + p0 + px0];
      #pragma unroll
      for (int e = 0; e < 8; e++) {
        h4 w;
        #pragma unroll
        for (int q = 0; q < 4; q++) w[q] = v[q][e];
        *(h4*)&ut[(px0 + e) * 392 + c4] = w;
      }
    }
  }
  __syncthreads();
  int px = t & 63, seg = t >> 6;
  float s = 0.f, ss = 0.f;
  #pragma unroll
  for (int j = 0; j < 6; j++) {
    h8 v = *(const h8*)&ut[px * 392 + seg * 48 + j * 8];
    #pragma unroll
    for (int e = 0; e < 8; e++) { float f = (float)v[e]; s += f; ss += f * f; }
  }
  red[seg][px] = s; red2[seg][px] = ss;
  __syncthreads();
  if (t < 64) {
    float st = 0.f, sst = 0.f;
    #pragma unroll
    for (int sg = 0; sg < 8; sg++) { st += red[sg][t]; sst += red2[sg][t]; }
    float m = st * (1.f/384.f);
    float var = sst * (1.f/384.f) - m * m;
    muL[t] = m; rsL[t] = rsqrtf(var + 1e-5f);
  }
  __syncthreads();
  const _Float16* zb = zs + (size_t)b * C_N * P_N;
  #pragma unroll
  for (int i = 0; i < 2; i++) {
    int id = t + 512 * i;
    if (id < 768) {
      int px0 = (id & 7) * 8;
      int c4 = (id >> 3) * 4;
      f4 g4 = *(const f4*)&lng[c4];
      f4 b4 = *(const f4*)&lnbv[c4];
      h8 z[4];
      #pragma unroll
      for (int q = 0; q < 4; q++)
        z[q] = *(const h8*)&zb[(size_t)(c4 + q) * P_N + p0 + px0];
      #pragma unroll
      for (int e = 0; e < 8; e++) {
        int p = px0 + e;
        h4 y = *(const h4*)&ut[p * 392 + c4];
        float mu = muL[p], rs = rsL[p];
        #pragma unroll
        for (int q = 0; q < 4; q++) {
          float f = ((float)y[q] - mu) * rs * g4[q] + b4[q];
          y[q] = (_Float16)(f * (float)z[q][e]);
        }
        *(h4*)&ut[p * 392 + c4] = y;
      }
    }
  }
  __syncthreads();
  int lane = t & 63, wave = t >> 6;
  int quad = lane >> 4, l15 = lane & 15;
  int n0 = wave * 48;
  f4 acc[4][3] = {};
  const _Float16* bw = owh + (size_t)(n0 + l15) * 384 + quad * 8;
  #pragma unroll
  for (int kc = 0; kc < 384; kc += 32) {
    h8 af[4], bf[3];
    #pragma unroll
    for (int i = 0; i < 4; i++)
      af[i] = *(const h8*)&ut[(i*16 + l15) * 392 + kc + quad*8];
    #pragma unroll
    for (int j = 0; j < 3; j++)
      bf[j] = *(const h8*)&bw[(size_t)(j*16) * 384 + kc];
    #pragma unroll
    for (int i = 0; i < 4; i++)
    #pragma unroll
    for (int j = 0; j < 3; j++)
      acc[i][j] = MFMA32(af[i], bf[j], acc[i][j]);
  }
  #pragma unroll
  for (int j = 0; j < 3; j++) {
    int d = n0 + j*16 + l15;
    float bias = ob[d];
    float* op = out + ((size_t)b*C_N + d) * P_N + p0;
    #pragma unroll
    for (int i = 0; i < 4; i++) {
      f4 v;
      #pragma unroll
      for (int r = 0; r < 4; r++) v[r] = acc[i][j][r] + bias;
      *(f4*)&op[i*16 + quad*4] = v;
    }
  }
}

extern "C" void kernel_launch(void* const* d_in, const int* in_sizes, int n_in,
                              void* d_out, int out_size, void* d_ws, size_t ws_size,
                              hipStream_t stream) {
  (void)in_sizes; (void)n_in; (void)out_size; (void)ws_size;
  const float* x    = (const float*)d_in[0];
  const float* fe   = (const float*)d_in[1];
  const float* dww  = (const float*)d_in[2];
  const float* dwb  = (const float*)d_in[3];
  const float* linw = (const float*)d_in[4];
  const float* linb = (const float*)d_in[5];
  const float* tokw = (const float*)d_in[6];
  const float* tokb = (const float*)d_in[7];
  const float* cc   = (const float*)d_in[8];
  const float* aa   = (const float*)d_in[9];
  const float* lng  = (const float*)d_in[10];
  const float* lnbv = (const float*)d_in[11];
  const float* outw = (const float*)d_in[12];
  const float* outb = (const float*)d_in[13];
  float* out = (float*)d_out;

  char* ws = (char*)d_ws;
  size_t off = 0;
  auto alloc = [&](size_t bytes) -> void* {
    void* p = ws + off;
    off += (bytes + 255) & ~(size_t)255;
    return p;
  };
  _Float16* lwh  = (_Float16*)alloc((size_t)768*384*2);
  _Float16* twh  = (_Float16*)alloc((size_t)384*384*2);
  _Float16* owh  = (_Float16*)alloc((size_t)384*384*2);
  _Float16* wmg  = (_Float16*)alloc((size_t)64*64*2);
  _Float16* wmtg = (_Float16*)alloc((size_t)64*64*2);
  _Float16* xdw  = (_Float16*)alloc((size_t)B_N*P_N*C_N*2);
  _Float16* xs   = (_Float16*)alloc((size_t)B_N*C_N*P_N*2);
  _Float16* zs   = (_Float16*)alloc((size_t)B_N*C_N*P_N*2);
  _Float16* gg   = (_Float16*)alloc((size_t)C_N*P_N*2);
  _Float16* xi   = xdw;   // xdw dead after k_gemm1

  k_setup<<<1152, 256, 0, stream>>>(linw, tokw, outw, lwh, twh, owh, wmg, wmtg);
  k_dwgate<<<1152, 256, 0, stream>>>(x, dww, dwb, xdw, fe, twh, tokb, cc, aa, gg);
  k_gemm1<<<1536, 256, 0, stream>>>(xdw, lwh, linb, xs, zs);
  k_dct<<<768, 256, 0, stream>>>(xs, gg, wmg, wmtg, xi);
  k_fuse<<<512, 512, 0, stream>>>(xi, zs, lng, lnbv, owh, outb, out);
}